// Round 1
// baseline (1518.008 us; speedup 1.0000x reference)
//
#include <hip/hip_runtime.h>

#define B_ 2
#define C_ 96
#define H_ 64
#define W_ 64
#define L_ 4096
#define DI_ 192
#define DS_ 16
#define DTR_ 6
#define XPW_ 38
#define ND_ 4
#define CH_ 64
#define NC_ 64

// direction map: sequence position l -> spatial index s (row-major h*W+w).
// Involution for every k (verified: T(4095-l) == 4095-T(l)), so it is its own inverse.
__device__ __forceinline__ int smap(int k, int l) {
  if (k == 0) return l;
  if (k == 1) return L_ - 1 - l;
  if (k == 2) return ((l & 63) << 6) | (l >> 6);
  int l2 = L_ - 1 - l;
  return ((l2 & 63) << 6) | (l2 >> 6);
}

__device__ __forceinline__ float wredsum(float v) {
#pragma unroll
  for (int o = 32; o > 0; o >>= 1) v += __shfl_down(v, o, 64);
  return __shfl(v, 0, 64);
}

// K1: LayerNorm over C.  x(B,C,L) -> xn(B,L,C)
__global__ void k_ln(const float* __restrict__ x, const float* __restrict__ g,
                     const float* __restrict__ bt, float* __restrict__ xn) {
  int s = blockIdx.x % L_;
  int b = blockIdx.x / L_;
  int lane = threadIdx.x;  // 64
  float v0 = x[((size_t)b * C_ + lane) * L_ + s];
  float v1 = (lane < 32) ? x[((size_t)b * C_ + 64 + lane) * L_ + s] : 0.f;
  float m = wredsum(v0 + v1) * (1.f / 96.f);
  float d0 = v0 - m;
  float d1 = (lane < 32) ? v1 - m : 0.f;
  float var = wredsum(d0 * d0 + d1 * d1) * (1.f / 96.f);
  float rstd = rsqrtf(var + 1e-5f);
  float* o = xn + ((size_t)b * L_ + s) * C_;
  o[lane] = d0 * rstd * g[lane] + bt[lane];
  if (lane < 32) o[64 + lane] = d1 * rstd * g[64 + lane] + bt[64 + lane];
}

// K2: in-projection. one block per (k,b,l), 384 threads = one output j each.
__global__ void k_inproj(const float* __restrict__ xn, const float* __restrict__ in_w,
                         float* __restrict__ xsr, float* __restrict__ zb) {
  int blk = blockIdx.x;
  int l = blk % L_;
  int kb = blk / L_;  // k*B+b
  int b = kb % B_;
  int k = kb / B_;
  int tid = threadIdx.x;  // 384
  __shared__ __align__(16) float row[C_];
  if (tid < C_) row[tid] = xn[((size_t)b * L_ + smap(k, l)) * C_ + tid];
  __syncthreads();
  const float4* w4 = (const float4*)(in_w + ((size_t)k * 384 + tid) * C_);
  const float4* r4 = (const float4*)row;
  float acc = 0.f;
#pragma unroll
  for (int i = 0; i < C_ / 4; ++i) {
    float4 a = r4[i], w = w4[i];
    acc += a.x * w.x + a.y * w.y + a.z * w.z + a.w * w.w;
  }
  size_t base = ((size_t)kb * L_ + l) * DI_;
  if (tid < DI_) xsr[base + tid] = acc;
  else zb[base + tid - DI_] = acc;
}

// K3: causal depthwise conv (k=4) + silu
__global__ void k_conv(const float* __restrict__ xsr, const float* __restrict__ cw,
                       const float* __restrict__ cb, float* __restrict__ xs) {
  int idx = blockIdx.x * blockDim.x + threadIdx.x;  // ND*B*L*DI
  int d = idx % DI_;
  int rest = idx / DI_;
  int l = rest % L_;
  int kb = rest / L_;
  int k = kb / B_;
  float acc = cb[k * DI_ + d];
  const float* w = cw + ((size_t)k * DI_ + d) * 4;
#pragma unroll
  for (int j = 0; j < 4; ++j) {
    int t = l - 3 + j;
    if (t >= 0) acc += xsr[((size_t)kb * L_ + t) * DI_ + d] * w[j];
  }
  xs[idx] = acc / (1.f + expf(-acc));  // silu
}

// K4: x-projection (192 -> 38)
__global__ void k_xproj(const float* __restrict__ xs, const float* __restrict__ xw,
                        float* __restrict__ xp) {
  int idx = blockIdx.x * blockDim.x + threadIdx.x;  // ND*B*L*XPW
  int r = idx % XPW_;
  int row = idx / XPW_;
  int k = (row / L_) / B_;
  const float4* a4 = (const float4*)(xs + (size_t)row * DI_);
  const float4* w4 = (const float4*)(xw + ((size_t)k * XPW_ + r) * DI_);
  float acc = 0.f;
#pragma unroll
  for (int i = 0; i < DI_ / 4; ++i) {
    float4 a = a4[i], w = w4[i];
    acc += a.x * w.x + a.y * w.y + a.z * w.z + a.w * w.w;
  }
  xp[idx] = acc;
}

// K5: delta = softplus(xp[:,:6] @ dt_w.T + dt_b)
__global__ void k_dt(const float* __restrict__ xp, const float* __restrict__ dw,
                     const float* __restrict__ db, float* __restrict__ dlt) {
  int idx = blockIdx.x * blockDim.x + threadIdx.x;  // ND*B*L*DI
  int d = idx % DI_;
  int row = idx / DI_;
  int k = (row / L_) / B_;
  const float* xrow = xp + (size_t)row * XPW_;
  const float* w = dw + ((size_t)k * DI_ + d) * DTR_;
  float acc = db[k * DI_ + d];
#pragma unroll
  for (int r = 0; r < DTR_; ++r) acc += xrow[r] * w[r];
  dlt[idx] = fmaxf(acc, 0.f) + log1pf(expf(-fabsf(acc)));  // stable softplus
}

// K6: scan phase 1 — per-chunk (P = exp(A*sumDelta), S = local scan from 0)
__global__ void k_scan1(const float* __restrict__ dlt, const float* __restrict__ xs,
                        const float* __restrict__ xp, const float* __restrict__ A_log,
                        float* __restrict__ Pb, float* __restrict__ Sb) {
  int blk = blockIdx.x;  // ND*B*NC
  int c = blk % NC_;
  int kb = blk / NC_;
  int k = kb / B_;
  int d = threadIdx.x;  // 192
  __shared__ float Bs[CH_][DS_];
  for (int i = threadIdx.x; i < CH_ * DS_; i += DI_) {
    int t = i / DS_, n = i % DS_;
    Bs[t][n] = xp[((size_t)kb * L_ + c * CH_ + t) * XPW_ + DTR_ + n];
  }
  float A2[DS_];
  const float* al = A_log + ((size_t)k * DI_ + d) * DS_;
#pragma unroll
  for (int n = 0; n < DS_; ++n) A2[n] = -expf(al[n]) * 1.4426950408889634f;
  __syncthreads();
  float h[DS_];
#pragma unroll
  for (int n = 0; n < DS_; ++n) h[n] = 0.f;
  float sumd = 0.f;
  const size_t rowb = ((size_t)kb * L_ + c * CH_) * DI_ + d;
  for (int t = 0; t < CH_; ++t) {
    float de = dlt[rowb + (size_t)t * DI_];
    float xv = xs[rowb + (size_t)t * DI_];
    float dx = de * xv;
    sumd += de;
#pragma unroll
    for (int n = 0; n < DS_; ++n)
      h[n] = fmaf(exp2f(A2[n] * de), h[n], dx * Bs[t][n]);
  }
  size_t base = (((size_t)kb * NC_ + c) * DI_ + d) * DS_;
#pragma unroll
  for (int n = 0; n < DS_; ++n) {
    Pb[base + n] = exp2f(A2[n] * sumd);
    Sb[base + n] = h[n];
  }
}

// K7: scan phase 2 — serial chunk combine; writes h_in in-place into Sb
__global__ void k_scan2(const float* __restrict__ Pb, float* __restrict__ Sb) {
  int gid = blockIdx.x * blockDim.x + threadIdx.x;  // ND*B*DI*DS = 24576
  int dn = gid % (DI_ * DS_);
  int kb = gid / (DI_ * DS_);
  size_t base = (size_t)kb * NC_ * DI_ * DS_ + dn;
  float h = 0.f;
  for (int c = 0; c < NC_; ++c) {
    size_t i = base + (size_t)c * DI_ * DS_;
    float p = Pb[i], s = Sb[i];
    Sb[i] = h;  // h_in for chunk c
    h = fmaf(p, h, s);
  }
}

// K8: scan phase 3 — rerun with h_in, fuse y = (scan + xs*D) * silu(z)
__global__ void k_scan3(const float* __restrict__ dlt, const float* __restrict__ xs,
                        const float* __restrict__ xp, const float* __restrict__ A_log,
                        const float* __restrict__ hin, const float* __restrict__ Dpp,
                        const float* __restrict__ zb, float* __restrict__ gb) {
  int blk = blockIdx.x;
  int c = blk % NC_;
  int kb = blk / NC_;
  int k = kb / B_;
  int d = threadIdx.x;  // 192
  __shared__ float Bs[CH_][DS_], Cs[CH_][DS_];
  for (int i = threadIdx.x; i < CH_ * DS_; i += DI_) {
    int t = i / DS_, n = i % DS_;
    size_t rb = ((size_t)kb * L_ + c * CH_ + t) * XPW_ + DTR_;
    Bs[t][n] = xp[rb + n];
    Cs[t][n] = xp[rb + DS_ + n];
  }
  float A2[DS_];
  const float* al = A_log + ((size_t)k * DI_ + d) * DS_;
#pragma unroll
  for (int n = 0; n < DS_; ++n) A2[n] = -expf(al[n]) * 1.4426950408889634f;
  float h[DS_];
  size_t hbase = (((size_t)kb * NC_ + c) * DI_ + d) * DS_;
#pragma unroll
  for (int n = 0; n < DS_; ++n) h[n] = hin[hbase + n];
  float Dv = Dpp[k * DI_ + d];
  __syncthreads();
  const size_t rowb = ((size_t)kb * L_ + c * CH_) * DI_ + d;
  for (int t = 0; t < CH_; ++t) {
    float de = dlt[rowb + (size_t)t * DI_];
    float xv = xs[rowb + (size_t)t * DI_];
    float dx = de * xv;
    float acc = 0.f;
#pragma unroll
    for (int n = 0; n < DS_; ++n) {
      h[n] = fmaf(exp2f(A2[n] * de), h[n], dx * Bs[t][n]);
      acc = fmaf(h[n], Cs[t][n], acc);
    }
    float y = acc + xv * Dv;
    float zv = zb[rowb + (size_t)t * DI_];
    gb[rowb + (size_t)t * DI_] = y * (zv / (1.f + expf(-zv)));
  }
}

// K9: out-projection (192 -> 96), 4 rows per block
__global__ void k_outproj(const float* __restrict__ gb, const float* __restrict__ ow,
                          float* __restrict__ yo) {
  int blk = blockIdx.x;  // ND*B*(L/4)
  int lg = blk % (L_ / 4);
  int kb = blk / (L_ / 4);
  int k = kb / B_;
  int l0 = lg * 4;
  int tid = threadIdx.x;  // 384
  __shared__ __align__(16) float gs[4][DI_];
  for (int i = tid; i < 4 * DI_; i += 384) {
    gs[i / DI_][i % DI_] = gb[((size_t)kb * L_ + l0 + i / DI_) * DI_ + i % DI_];
  }
  __syncthreads();
  int r = tid / C_;
  int j = tid % C_;
  const float4* w4 = (const float4*)(ow + ((size_t)k * C_ + j) * DI_);
  const float4* a4 = (const float4*)gs[r];
  float acc = 0.f;
#pragma unroll
  for (int i = 0; i < DI_ / 4; ++i) {
    float4 a = a4[i], w = w4[i];
    acc += a.x * w.x + a.y * w.y + a.z * w.z + a.w * w.w;
  }
  yo[((size_t)kb * L_ + l0 + r) * C_ + j] = acc;
}

// K10: merge 4 directions + residual add (xh)
__global__ void k_merge(const float* __restrict__ yo, const float* __restrict__ mw,
                        const float* __restrict__ mb, const float* __restrict__ x,
                        float* __restrict__ xr) {
  int blk = blockIdx.x;  // B*(L/4)
  int sg = blk % (L_ / 4);
  int b = blk / (L_ / 4);
  int s0 = sg * 4;
  int tid = threadIdx.x;  // 384
  __shared__ __align__(16) float ys[4][4 * C_];
  for (int i = tid; i < 4 * 4 * C_; i += 384) {
    int r = i / (4 * C_);
    int q = i % (4 * C_);
    int k = q / C_, j = q % C_;
    int l = smap(k, s0 + r);  // smap is its own inverse
    ys[r][q] = yo[(((size_t)k * B_ + b) * L_ + l) * C_ + j];
  }
  __syncthreads();
  int r = tid / C_;
  int cc = tid % C_;
  int s = s0 + r;
  const float4* w4 = (const float4*)(mw + (size_t)cc * (4 * C_));
  const float4* a4 = (const float4*)ys[r];
  float acc = mb[cc];
#pragma unroll
  for (int i = 0; i < C_; ++i) {
    float4 a = a4[i], w = w4[i];
    acc += a.x * w.x + a.y * w.y + a.z * w.z + a.w * w.w;
  }
  xr[((size_t)b * L_ + s) * C_ + cc] = x[((size_t)b * C_ + cc) * L_ + s] + acc;
}

// K11: FFN layer 1 fused with LN (96 -> 384) + exact gelu
__global__ void k_ffn1(const float* __restrict__ xr, const float* __restrict__ fg,
                       const float* __restrict__ fb, const float* __restrict__ w1,
                       const float* __restrict__ b1, float* __restrict__ hb) {
  int s = blockIdx.x % L_;
  int b = blockIdx.x / L_;
  int tid = threadIdx.x;  // 384
  __shared__ __align__(16) float row[C_];
  __shared__ __align__(16) float nrm[C_];
  __shared__ float st[2];
  if (tid < C_) row[tid] = xr[((size_t)b * L_ + s) * C_ + tid];
  __syncthreads();
  if (tid < 64) {
    float v0 = row[tid];
    float v1 = (tid < 32) ? row[64 + tid] : 0.f;
    float m = wredsum(v0 + v1) * (1.f / 96.f);
    float d0 = v0 - m;
    float d1 = (tid < 32) ? v1 - m : 0.f;
    float var = wredsum(d0 * d0 + d1 * d1) * (1.f / 96.f);
    if (tid == 0) { st[0] = m; st[1] = rsqrtf(var + 1e-5f); }
  }
  __syncthreads();
  if (tid < C_) nrm[tid] = (row[tid] - st[0]) * st[1] * fg[tid] + fb[tid];
  __syncthreads();
  const float4* w4 = (const float4*)(w1 + (size_t)tid * C_);
  const float4* a4 = (const float4*)nrm;
  float acc = b1[tid];
#pragma unroll
  for (int i = 0; i < C_ / 4; ++i) {
    float4 a = a4[i], w = w4[i];
    acc += a.x * w.x + a.y * w.y + a.z * w.z + a.w * w.w;
  }
  hb[((size_t)b * L_ + s) * (4 * C_) + tid] =
      0.5f * acc * (1.f + erff(acc * 0.70710678118654752f));
}

// K12: FFN layer 2 (384 -> 96) + residual, transpose to (B,C,H,W)
__global__ void k_ffn2(const float* __restrict__ hb, const float* __restrict__ w2,
                       const float* __restrict__ b2, const float* __restrict__ xr,
                       float* __restrict__ out) {
  int blk = blockIdx.x;  // B*(L/2)
  int sg = blk % (L_ / 2);
  int b = blk / (L_ / 2);
  int s0 = sg * 2;
  int tid = threadIdx.x;  // 192
  __shared__ __align__(16) float hs[2][4 * C_];
  for (int i = tid; i < 2 * 4 * C_; i += 192) {
    hs[i / (4 * C_)][i % (4 * C_)] = hb[((size_t)b * L_ + s0 + i / (4 * C_)) * (4 * C_) + i % (4 * C_)];
  }
  __syncthreads();
  int r = tid / C_;
  int cc = tid % C_;
  int s = s0 + r;
  const float4* w4 = (const float4*)(w2 + (size_t)cc * (4 * C_));
  const float4* a4 = (const float4*)hs[r];
  float acc = b2[cc];
#pragma unroll
  for (int i = 0; i < C_; ++i) {
    float4 a = a4[i], w = w4[i];
    acc += a.x * w.x + a.y * w.y + a.z * w.z + a.w * w.w;
  }
  out[((size_t)b * C_ + cc) * L_ + s] = xr[((size_t)b * L_ + s) * C_ + cc] + acc;
}

extern "C" void kernel_launch(void* const* d_in, const int* in_sizes, int n_in,
                              void* d_out, int out_size, void* d_ws, size_t ws_size,
                              hipStream_t stream) {
  const float* x       = (const float*)d_in[0];
  const float* norm_g  = (const float*)d_in[1];
  const float* norm_b  = (const float*)d_in[2];
  const float* in_w    = (const float*)d_in[3];
  const float* conv_w  = (const float*)d_in[4];
  const float* conv_b  = (const float*)d_in[5];
  const float* xproj_w = (const float*)d_in[6];
  const float* dt_w    = (const float*)d_in[7];
  const float* dt_b    = (const float*)d_in[8];
  const float* A_log   = (const float*)d_in[9];
  const float* Dp      = (const float*)d_in[10];
  const float* out_w   = (const float*)d_in[11];
  const float* merge_w = (const float*)d_in[12];
  const float* merge_b = (const float*)d_in[13];
  const float* ffn_g   = (const float*)d_in[14];
  const float* ffn_be  = (const float*)d_in[15];
  const float* ffn_w1  = (const float*)d_in[16];
  const float* ffn_b1  = (const float*)d_in[17];
  const float* ffn_w2  = (const float*)d_in[18];
  const float* ffn_b2  = (const float*)d_in[19];
  float* out = (float*)d_out;

  // workspace layout (floats). total = 30,343,168 floats = 121.4 MB
  float* ws = (float*)d_ws;
  size_t o = 0;
  float* xn  = ws + o; o += (size_t)B_ * L_ * C_;           // 786,432
  float* xsr = ws + o; o += (size_t)ND_ * B_ * L_ * DI_;    // 6,291,456 (reused as gb)
  float* zb  = ws + o; o += (size_t)ND_ * B_ * L_ * DI_;    // 6,291,456 (reused as hb)
  float* xs  = ws + o; o += (size_t)ND_ * B_ * L_ * DI_;    // 6,291,456
  float* xp  = ws + o; o += (size_t)ND_ * B_ * L_ * XPW_;   // 1,245,184
  float* dlt = ws + o; o += (size_t)ND_ * B_ * L_ * DI_;    // 6,291,456 (reused as yo+xr)
  float* Pb  = ws + o; o += (size_t)ND_ * B_ * NC_ * DI_ * DS_;  // 1,572,864
  float* Sb  = ws + o; o += (size_t)ND_ * B_ * NC_ * DI_ * DS_;  // 1,572,864 (becomes hin)
  // stream-ordered aliases (producer kernel strictly after last consumer of original):
  float* gb = xsr;                                 // phase-3 gated output
  float* yo = dlt;                                 // out-proj result (3,145,728 floats)
  float* xr = dlt + (size_t)ND_ * B_ * L_ * C_;    // merge+residual (786,432 floats)
  float* hb = zb;                                  // ffn hidden

  k_ln     <<<B_ * L_, 64, 0, stream>>>(x, norm_g, norm_b, xn);
  k_inproj <<<ND_ * B_ * L_, 384, 0, stream>>>(xn, in_w, xsr, zb);
  k_conv   <<<(ND_ * B_ * L_ * DI_) / 256, 256, 0, stream>>>(xsr, conv_w, conv_b, xs);
  k_xproj  <<<(ND_ * B_ * L_ * XPW_) / 256, 256, 0, stream>>>(xs, xproj_w, xp);
  k_dt     <<<(ND_ * B_ * L_ * DI_) / 256, 256, 0, stream>>>(xp, dt_w, dt_b, dlt);
  k_scan1  <<<ND_ * B_ * NC_, DI_, 0, stream>>>(dlt, xs, xp, A_log, Pb, Sb);
  k_scan2  <<<(ND_ * B_ * DI_ * DS_) / 256, 256, 0, stream>>>(Pb, Sb);
  k_scan3  <<<ND_ * B_ * NC_, DI_, 0, stream>>>(dlt, xs, xp, A_log, Sb, Dp, zb, gb);
  k_outproj<<<ND_ * B_ * (L_ / 4), 384, 0, stream>>>(gb, out_w, yo);
  k_merge  <<<B_ * (L_ / 4), 384, 0, stream>>>(yo, merge_w, merge_b, x, xr);
  k_ffn1   <<<B_ * L_, 384, 0, stream>>>(xr, ffn_g, ffn_be, ffn_w1, ffn_b1, hb);
  k_ffn2   <<<B_ * (L_ / 2), 192, 0, stream>>>(hb, ffn_w2, ffn_b2, xr, out);
}

// Round 2
// 609.737 us; speedup vs baseline: 2.4896x; 2.4896x over previous
//
#include <hip/hip_runtime.h>

#define B_ 2
#define C_ 96
#define L_ 4096
#define DI_ 192
#define DS_ 16
#define DTR_ 6
#define ND_ 4
#define CH_ 64
#define NC_ 64

// direction map: sequence position l -> spatial index s (row-major h*W+w).
// Involution for every k, so it is its own inverse.
__device__ __forceinline__ int smap(int k, int l) {
  if (k == 0) return l;
  if (k == 1) return L_ - 1 - l;
  if (k == 2) return ((l & 63) << 6) | (l >> 6);
  int l2 = L_ - 1 - l;
  return ((l2 & 63) << 6) | (l2 >> 6);
}

__device__ __forceinline__ float sp_softplus(float v) {
  return fmaxf(v, 0.f) + log1pf(expf(-fabsf(v)));
}
__device__ __forceinline__ float silu(float v) { return v / (1.f + expf(-v)); }
__device__ __forceinline__ float gelu(float v) {
  return 0.5f * v * (1.f + erff(v * 0.70710678118654752f));
}

// ---- generic 48-deep K-step: acc[TM][TN] += A^T-tile x W^T-tile ----
template <int TM, int TN>
__device__ __forceinline__ void mm48(const float* __restrict__ At, const float* __restrict__ Wt,
                                     int lda, int ldw, int r0, int j0, float acc[TM][TN]) {
#pragma unroll 4
  for (int kk = 0; kk < 48; ++kk) {
    float a[TM], w[TN];
#pragma unroll
    for (int i = 0; i < TM; i += 4) *(float4*)&a[i] = *(const float4*)&At[kk * lda + r0 + i];
#pragma unroll
    for (int j = 0; j < TN; j += 4) *(float4*)&w[j] = *(const float4*)&Wt[kk * ldw + j0 + j];
#pragma unroll
    for (int i = 0; i < TM; ++i)
#pragma unroll
      for (int j = 0; j < TN; ++j) acc[i][j] = fmaf(a[i], w[j], acc[i][j]);
  }
}

// K1: LayerNorm over C with coalesced loads.  x(B,C,L) -> xn(B,L,C)
__global__ __launch_bounds__(256) void k_ln(const float* __restrict__ x, const float* __restrict__ g,
                                            const float* __restrict__ bt, float* __restrict__ xn) {
  int b = blockIdx.x / 64;
  int s0 = (blockIdx.x % 64) * 64;
  int tid = threadIdx.x;
  __shared__ float X[96 * 65];
  __shared__ float Ms[64], Rs[64];
  for (int i = tid; i < 96 * 64; i += 256) {
    int c = i / 64, ls = i % 64;
    X[c * 65 + ls] = x[((size_t)b * 96 + c) * L_ + s0 + ls];
  }
  __syncthreads();
  {
    int ls = tid >> 2, q = tid & 3;
    float s1 = 0.f, s2 = 0.f;
    for (int c = q; c < 96; c += 4) {
      float v = X[c * 65 + ls];
      s1 += v; s2 += v * v;
    }
    s1 += __shfl_xor(s1, 1); s1 += __shfl_xor(s1, 2);
    s2 += __shfl_xor(s2, 1); s2 += __shfl_xor(s2, 2);
    if (q == 0) {
      float m = s1 * (1.f / 96.f);
      Ms[ls] = m;
      Rs[ls] = rsqrtf(s2 * (1.f / 96.f) - m * m + 1e-5f);
    }
  }
  __syncthreads();
  for (int i = tid; i < 96 * 64; i += 256) {
    int c = i % 96, ls = i / 96;
    float v = (X[c * 65 + ls] - Ms[ls]) * Rs[ls] * g[c] + bt[c];
    xn[((size_t)b * L_ + s0 + ls) * 96 + c] = v;
  }
}

// K2: build fused delta/B/C weight: Wf[k][256][192]
// rows 0..191: Wd = dt_w @ xproj_w[:6];  rows 192..223: xproj rows 6..37;  rest 0
__global__ void k_prep(const float* __restrict__ dt_w, const float* __restrict__ xproj_w,
                       float* __restrict__ Wf) {
  int idx = blockIdx.x * 256 + threadIdx.x;  // 4*256*192
  int k = idx / (256 * 192);
  int r = idx % (256 * 192);
  int j = r / 192, i = r % 192;
  float v = 0.f;
  if (j < 192) {
#pragma unroll
    for (int r6 = 0; r6 < DTR_; ++r6)
      v += dt_w[((size_t)k * 192 + j) * DTR_ + r6] * xproj_w[((size_t)k * 38 + r6) * 192 + i];
  } else if (j < 224) {
    v = xproj_w[((size_t)k * 38 + 6 + (j - 192)) * 192 + i];
  }
  Wf[idx] = v;
}

// K3: in-projection GEMM: M=4096/kb, N=384 (6 ntiles), K=96
__global__ __launch_bounds__(128) void k_inproj(const float* __restrict__ xn, const float* __restrict__ in_w,
                                                float* __restrict__ xsr, float* __restrict__ zb) {
  int bx = blockIdx.x;
  int nt = bx % 6;
  int lt = (bx / 6) % 32;
  int kb = bx / 192;
  int k = kb / B_, b = kb % B_;
  int l0 = lt * 128;
  __shared__ float At[48 * 130];
  __shared__ float Wt[48 * 66];
  int tid = threadIdx.x;
  int tx = tid % 8, ty = tid / 8;
  int r0 = ty * 8, j0 = tx * 8;
  float acc[8][8];
#pragma unroll
  for (int i = 0; i < 8; ++i)
#pragma unroll
    for (int j = 0; j < 8; ++j) acc[i][j] = 0.f;
  for (int ks = 0; ks < 2; ++ks) {
    int k0 = ks * 48;
    for (int i = tid; i < 128 * 12; i += 128) {
      int row = i % 128, cg = i / 128;
      int s = smap(k, l0 + row);
      float4 v = *(const float4*)(xn + ((size_t)b * L_ + s) * 96 + k0 + 4 * cg);
      float* d = &At[(4 * cg) * 130 + row];
      d[0] = v.x; d[130] = v.y; d[260] = v.z; d[390] = v.w;
    }
    for (int i = tid; i < 64 * 12; i += 128) {
      int row = i % 64, cg = i / 64;
      float4 v = *(const float4*)(in_w + ((size_t)k * 384 + nt * 64 + row) * 96 + k0 + 4 * cg);
      float* d = &Wt[(4 * cg) * 66 + row];
      d[0] = v.x; d[66] = v.y; d[132] = v.z; d[198] = v.w;
    }
    __syncthreads();
    mm48<8, 8>(At, Wt, 130, 66, r0, j0, acc);
    __syncthreads();
  }
  int jg = nt * 64 + j0;
  float* dst = (jg < 192) ? xsr : zb;
  int jo = (jg < 192) ? jg : jg - 192;
#pragma unroll
  for (int i = 0; i < 8; ++i) {
    size_t rb = ((size_t)kb * L_ + l0 + r0 + i) * 192 + jo;
    *(float4*)&dst[rb] = make_float4(acc[i][0], acc[i][1], acc[i][2], acc[i][3]);
    *(float4*)&dst[rb + 4] = make_float4(acc[i][4], acc[i][5], acc[i][6], acc[i][7]);
  }
}

// K4: causal depthwise conv (k=4) + silu
__global__ void k_conv(const float* __restrict__ xsr, const float* __restrict__ cw,
                       const float* __restrict__ cb, float* __restrict__ xs) {
  int idx = blockIdx.x * blockDim.x + threadIdx.x;
  int d = idx % DI_;
  int rest = idx / DI_;
  int l = rest % L_;
  int kb = rest / L_;
  int k = kb / B_;
  float acc = cb[k * DI_ + d];
  const float* w = cw + ((size_t)k * DI_ + d) * 4;
#pragma unroll
  for (int j = 0; j < 4; ++j) {
    int t = l - 3 + j;
    if (t >= 0) acc += xsr[((size_t)kb * L_ + t) * DI_ + d] * w[j];
  }
  xs[idx] = silu(acc);
}

// K5: fused delta/B/C GEMM: N=256 (4 ntiles; 192 delta + 32 BC + 32 pad), K=192
__global__ __launch_bounds__(128) void k_dgemm(const float* __restrict__ xs, const float* __restrict__ Wf,
                                               const float* __restrict__ dt_b,
                                               float* __restrict__ dlt, float* __restrict__ xbc) {
  int bx = blockIdx.x;
  int nt = bx % 4;
  int lt = (bx / 4) % 32;
  int kb = bx / 128;
  int k = kb / B_;
  int l0 = lt * 128;
  __shared__ float At[48 * 130];
  __shared__ float Wt[48 * 66];
  int tid = threadIdx.x;
  int tx = tid % 8, ty = tid / 8;
  int r0 = ty * 8, j0 = tx * 8;
  float acc[8][8];
#pragma unroll
  for (int i = 0; i < 8; ++i)
#pragma unroll
    for (int j = 0; j < 8; ++j) acc[i][j] = 0.f;
  for (int ks = 0; ks < 4; ++ks) {
    int k0 = ks * 48;
    for (int i = tid; i < 128 * 12; i += 128) {
      int row = i % 128, cg = i / 128;
      float4 v = *(const float4*)(xs + ((size_t)kb * L_ + l0 + row) * 192 + k0 + 4 * cg);
      float* d = &At[(4 * cg) * 130 + row];
      d[0] = v.x; d[130] = v.y; d[260] = v.z; d[390] = v.w;
    }
    for (int i = tid; i < 64 * 12; i += 128) {
      int row = i % 64, cg = i / 64;
      float4 v = *(const float4*)(Wf + ((size_t)k * 256 + nt * 64 + row) * 192 + k0 + 4 * cg);
      float* d = &Wt[(4 * cg) * 66 + row];
      d[0] = v.x; d[66] = v.y; d[132] = v.z; d[198] = v.w;
    }
    __syncthreads();
    mm48<8, 8>(At, Wt, 130, 66, r0, j0, acc);
    __syncthreads();
  }
  int jg = nt * 64 + j0;
  if (jg < 192) {
#pragma unroll
    for (int i = 0; i < 8; ++i) {
      size_t rb = ((size_t)kb * L_ + l0 + r0 + i) * 192 + jg;
      float o[8];
#pragma unroll
      for (int j = 0; j < 8; ++j) o[j] = sp_softplus(acc[i][j] + dt_b[k * 192 + jg + j]);
      *(float4*)&dlt[rb] = make_float4(o[0], o[1], o[2], o[3]);
      *(float4*)&dlt[rb + 4] = make_float4(o[4], o[5], o[6], o[7]);
    }
  } else if (jg < 224) {
    int jo = jg - 192;
#pragma unroll
    for (int i = 0; i < 8; ++i) {
      size_t rb = ((size_t)kb * L_ + l0 + r0 + i) * 32 + jo;
      *(float4*)&xbc[rb] = make_float4(acc[i][0], acc[i][1], acc[i][2], acc[i][3]);
      *(float4*)&xbc[rb + 4] = make_float4(acc[i][4], acc[i][5], acc[i][6], acc[i][7]);
    }
  }
}

// K6: scan phase 1 — per-chunk (P = exp(A*sumDelta), S = local scan from 0)
__global__ void k_scan1(const float* __restrict__ dlt, const float* __restrict__ xs,
                        const float* __restrict__ xbc, const float* __restrict__ A_log,
                        float* __restrict__ Pb, float* __restrict__ Sb) {
  int blk = blockIdx.x;
  int c = blk % NC_;
  int kb = blk / NC_;
  int k = kb / B_;
  int d = threadIdx.x;  // 192
  __shared__ float Bs[CH_][DS_];
  for (int i = threadIdx.x; i < CH_ * DS_; i += DI_) {
    int t = i / DS_, n = i % DS_;
    Bs[t][n] = xbc[((size_t)kb * L_ + c * CH_ + t) * 32 + n];
  }
  float A2[DS_];
  const float* al = A_log + ((size_t)k * DI_ + d) * DS_;
#pragma unroll
  for (int n = 0; n < DS_; ++n) A2[n] = -expf(al[n]) * 1.4426950408889634f;
  __syncthreads();
  float h[DS_];
#pragma unroll
  for (int n = 0; n < DS_; ++n) h[n] = 0.f;
  float sumd = 0.f;
  const size_t rowb = ((size_t)kb * L_ + c * CH_) * DI_ + d;
  for (int t = 0; t < CH_; ++t) {
    float de = dlt[rowb + (size_t)t * DI_];
    float xv = xs[rowb + (size_t)t * DI_];
    float dx = de * xv;
    sumd += de;
#pragma unroll
    for (int n = 0; n < DS_; ++n)
      h[n] = fmaf(exp2f(A2[n] * de), h[n], dx * Bs[t][n]);
  }
  size_t base = (((size_t)kb * NC_ + c) * DI_ + d) * DS_;
#pragma unroll
  for (int n = 0; n < DS_; ++n) {
    Pb[base + n] = exp2f(A2[n] * sumd);
    Sb[base + n] = h[n];
  }
}

// K7: scan phase 2 — serial chunk combine; writes h_in in-place into Sb
__global__ void k_scan2(const float* __restrict__ Pb, float* __restrict__ Sb) {
  int gid = blockIdx.x * blockDim.x + threadIdx.x;  // 24576
  int dn = gid % (DI_ * DS_);
  int kb = gid / (DI_ * DS_);
  size_t base = (size_t)kb * NC_ * DI_ * DS_ + dn;
  float h = 0.f;
  for (int c = 0; c < NC_; ++c) {
    size_t i = base + (size_t)c * DI_ * DS_;
    float p = Pb[i], s = Sb[i];
    Sb[i] = h;
    h = fmaf(p, h, s);
  }
}

// K8: scan phase 3 — rerun with h_in, fuse y = (scan + xs*D) * silu(z)
__global__ void k_scan3(const float* __restrict__ dlt, const float* __restrict__ xs,
                        const float* __restrict__ xbc, const float* __restrict__ A_log,
                        const float* __restrict__ hin, const float* __restrict__ Dpp,
                        const float* __restrict__ zb, float* __restrict__ gb) {
  int blk = blockIdx.x;
  int c = blk % NC_;
  int kb = blk / NC_;
  int k = kb / B_;
  int d = threadIdx.x;  // 192
  __shared__ float Bs[CH_][DS_], Cs[CH_][DS_];
  for (int i = threadIdx.x; i < CH_ * DS_; i += DI_) {
    int t = i / DS_, n = i % DS_;
    size_t rb = ((size_t)kb * L_ + c * CH_ + t) * 32;
    Bs[t][n] = xbc[rb + n];
    Cs[t][n] = xbc[rb + 16 + n];
  }
  float A2[DS_];
  const float* al = A_log + ((size_t)k * DI_ + d) * DS_;
#pragma unroll
  for (int n = 0; n < DS_; ++n) A2[n] = -expf(al[n]) * 1.4426950408889634f;
  float h[DS_];
  size_t hbase = (((size_t)kb * NC_ + c) * DI_ + d) * DS_;
#pragma unroll
  for (int n = 0; n < DS_; ++n) h[n] = hin[hbase + n];
  float Dv = Dpp[k * DI_ + d];
  __syncthreads();
  const size_t rowb = ((size_t)kb * L_ + c * CH_) * DI_ + d;
  for (int t = 0; t < CH_; ++t) {
    float de = dlt[rowb + (size_t)t * DI_];
    float xv = xs[rowb + (size_t)t * DI_];
    float dx = de * xv;
    float acc = 0.f;
#pragma unroll
    for (int n = 0; n < DS_; ++n) {
      h[n] = fmaf(exp2f(A2[n] * de), h[n], dx * Bs[t][n]);
      acc = fmaf(h[n], Cs[t][n], acc);
    }
    float y = acc + xv * Dv;
    float zv = zb[rowb + (size_t)t * DI_];
    gb[rowb + (size_t)t * DI_] = y * silu(zv);
  }
}

// K9: out-projection GEMM: N=96, K=192
__global__ __launch_bounds__(192) void k_outproj(const float* __restrict__ gb, const float* __restrict__ ow,
                                                 float* __restrict__ yo) {
  int bx = blockIdx.x;
  int lt = bx % 32;
  int kb = bx / 32;
  int k = kb / B_;
  int l0 = lt * 128;
  __shared__ float At[48 * 130];
  __shared__ float Wt[48 * 98];
  int tid = threadIdx.x;
  int tx = tid % 12, ty = tid / 12;
  int r0 = ty * 8, j0 = tx * 8;
  float acc[8][8];
#pragma unroll
  for (int i = 0; i < 8; ++i)
#pragma unroll
    for (int j = 0; j < 8; ++j) acc[i][j] = 0.f;
  for (int ks = 0; ks < 4; ++ks) {
    int k0 = ks * 48;
    for (int i = tid; i < 128 * 12; i += 192) {
      int row = i % 128, cg = i / 128;
      float4 v = *(const float4*)(gb + ((size_t)kb * L_ + l0 + row) * 192 + k0 + 4 * cg);
      float* d = &At[(4 * cg) * 130 + row];
      d[0] = v.x; d[130] = v.y; d[260] = v.z; d[390] = v.w;
    }
    for (int i = tid; i < 96 * 12; i += 192) {
      int row = i % 96, cg = i / 96;
      float4 v = *(const float4*)(ow + ((size_t)k * 96 + row) * 192 + k0 + 4 * cg);
      float* d = &Wt[(4 * cg) * 98 + row];
      d[0] = v.x; d[98] = v.y; d[196] = v.z; d[294] = v.w;
    }
    __syncthreads();
    mm48<8, 8>(At, Wt, 130, 98, r0, j0, acc);
    __syncthreads();
  }
#pragma unroll
  for (int i = 0; i < 8; ++i) {
    size_t rb = ((size_t)kb * L_ + l0 + r0 + i) * 96 + j0;
    *(float4*)&yo[rb] = make_float4(acc[i][0], acc[i][1], acc[i][2], acc[i][3]);
    *(float4*)&yo[rb + 4] = make_float4(acc[i][4], acc[i][5], acc[i][6], acc[i][7]);
  }
}

// K10: merge GEMM with direction gather: M=8192, N=96 (2 ntiles of 48), K=384
__global__ __launch_bounds__(192) void k_merge(const float* __restrict__ yo, const float* __restrict__ mw,
                                               const float* __restrict__ mb, const float* __restrict__ x,
                                               float* __restrict__ xr) {
  int bx = blockIdx.x;
  int nt = bx % 2;
  int mt = (bx / 2) % 64;
  int b = bx / 128;
  int s0 = mt * 64;
  __shared__ float At[48 * 66];
  __shared__ float Wt[48 * 50];
  int tid = threadIdx.x;
  int tx = tid % 12, ty = tid / 12;
  int r0 = ty * 4, j0 = tx * 4;
  float acc[4][4];
#pragma unroll
  for (int i = 0; i < 4; ++i)
#pragma unroll
    for (int j = 0; j < 4; ++j) acc[i][j] = 0.f;
  for (int ks = 0; ks < 8; ++ks) {
    int kq = ks / 2;
    int k0 = (ks % 2) * 48;
    for (int i = tid; i < 64 * 12; i += 192) {
      int row = i % 64, cg = i / 64;
      int l = smap(kq, s0 + row);
      float4 v = *(const float4*)(yo + (((size_t)kq * B_ + b) * L_ + l) * 96 + k0 + 4 * cg);
      float* d = &At[(4 * cg) * 66 + row];
      d[0] = v.x; d[66] = v.y; d[132] = v.z; d[198] = v.w;
    }
    for (int i = tid; i < 48 * 12; i += 192) {
      int row = i % 48, cg = i / 48;
      float4 v = *(const float4*)(mw + ((size_t)nt * 48 + row) * 384 + ks * 48 + 4 * cg);
      float* d = &Wt[(4 * cg) * 50 + row];
      d[0] = v.x; d[50] = v.y; d[100] = v.z; d[150] = v.w;
    }
    __syncthreads();
    mm48<4, 4>(At, Wt, 66, 50, r0, j0, acc);
    __syncthreads();
  }
  int jg = nt * 48 + j0;
#pragma unroll
  for (int i = 0; i < 4; ++i) {
    int s = s0 + r0 + i;
    float o[4];
#pragma unroll
    for (int j = 0; j < 4; ++j)
      o[j] = acc[i][j] + mb[jg + j] + x[((size_t)b * 96 + jg + j) * L_ + s];
    *(float4*)&xr[((size_t)b * L_ + s) * 96 + jg] = make_float4(o[0], o[1], o[2], o[3]);
  }
}

// K11: second LayerNorm (rows contiguous): xr -> nrm
__global__ __launch_bounds__(256) void k_ln2(const float* __restrict__ xr, const float* __restrict__ fg,
                                             const float* __restrict__ fb, float* __restrict__ nrm) {
  int g0 = blockIdx.x * 64;
  int r = threadIdx.x / 4, q = threadIdx.x & 3;
  const float* src = xr + ((size_t)(g0 + r)) * 96 + q * 24;
  float4 v[6];
  float s1 = 0.f, s2 = 0.f;
#pragma unroll
  for (int e = 0; e < 6; ++e) {
    v[e] = *(const float4*)(src + 4 * e);
    s1 += v[e].x + v[e].y + v[e].z + v[e].w;
    s2 += v[e].x * v[e].x + v[e].y * v[e].y + v[e].z * v[e].z + v[e].w * v[e].w;
  }
  s1 += __shfl_xor(s1, 1); s1 += __shfl_xor(s1, 2);
  s2 += __shfl_xor(s2, 1); s2 += __shfl_xor(s2, 2);
  float m = s1 * (1.f / 96.f);
  float rstd = rsqrtf(s2 * (1.f / 96.f) - m * m + 1e-5f);
  float* dst = nrm + ((size_t)(g0 + r)) * 96 + q * 24;
#pragma unroll
  for (int e = 0; e < 6; ++e) {
    int c = q * 24 + 4 * e;
    float4 o;
    o.x = (v[e].x - m) * rstd * fg[c] + fb[c];
    o.y = (v[e].y - m) * rstd * fg[c + 1] + fb[c + 1];
    o.z = (v[e].z - m) * rstd * fg[c + 2] + fb[c + 2];
    o.w = (v[e].w - m) * rstd * fg[c + 3] + fb[c + 3];
    *(float4*)(dst + 4 * e) = o;
  }
}

// K12: FFN layer 1 GEMM: M=8192, N=384 (6 ntiles), K=96, epilogue gelu
__global__ __launch_bounds__(128) void k_ffn1(const float* __restrict__ nrm, const float* __restrict__ w1,
                                              const float* __restrict__ b1, float* __restrict__ hb) {
  int bx = blockIdx.x;
  int nt = bx % 6;
  int mt = bx / 6;
  int g0 = mt * 128;
  __shared__ float At[48 * 130];
  __shared__ float Wt[48 * 66];
  int tid = threadIdx.x;
  int tx = tid % 8, ty = tid / 8;
  int r0 = ty * 8, j0 = tx * 8;
  float acc[8][8];
#pragma unroll
  for (int i = 0; i < 8; ++i)
#pragma unroll
    for (int j = 0; j < 8; ++j) acc[i][j] = 0.f;
  for (int ks = 0; ks < 2; ++ks) {
    int k0 = ks * 48;
    for (int i = tid; i < 128 * 12; i += 128) {
      int row = i % 128, cg = i / 128;
      float4 v = *(const float4*)(nrm + ((size_t)(g0 + row)) * 96 + k0 + 4 * cg);
      float* d = &At[(4 * cg) * 130 + row];
      d[0] = v.x; d[130] = v.y; d[260] = v.z; d[390] = v.w;
    }
    for (int i = tid; i < 64 * 12; i += 128) {
      int row = i % 64, cg = i / 64;
      float4 v = *(const float4*)(w1 + ((size_t)(nt * 64 + row)) * 96 + k0 + 4 * cg);
      float* d = &Wt[(4 * cg) * 66 + row];
      d[0] = v.x; d[66] = v.y; d[132] = v.z; d[198] = v.w;
    }
    __syncthreads();
    mm48<8, 8>(At, Wt, 130, 66, r0, j0, acc);
    __syncthreads();
  }
  int jg = nt * 64 + j0;
#pragma unroll
  for (int i = 0; i < 8; ++i) {
    size_t rb = ((size_t)(g0 + r0 + i)) * 384 + jg;
    float o[8];
#pragma unroll
    for (int j = 0; j < 8; ++j) o[j] = gelu(acc[i][j] + b1[jg + j]);
    *(float4*)&hb[rb] = make_float4(o[0], o[1], o[2], o[3]);
    *(float4*)&hb[rb + 4] = make_float4(o[4], o[5], o[6], o[7]);
  }
}

// K13: FFN layer 2 GEMM + residual + transposed store: M=8192, N=96 (2 ntiles of 48), K=384
__global__ __launch_bounds__(192) void k_ffn2(const float* __restrict__ hb, const float* __restrict__ w2,
                                              const float* __restrict__ b2, const float* __restrict__ xr,
                                              float* __restrict__ out) {
  int bx = blockIdx.x;
  int nt = bx % 2;
  int mt = bx / 2;
  int g0 = mt * 64;
  int b = g0 >> 12;
  int s0 = g0 & 4095;
  __shared__ float At[3264];  // 48x66 for staging; reused as 48x68 transpose buffer
  __shared__ float Wt[48 * 50];
  int tid = threadIdx.x;
  int tx = tid % 12, ty = tid / 12;
  int r0 = ty * 4, j0 = tx * 4;
  float acc[4][4];
#pragma unroll
  for (int i = 0; i < 4; ++i)
#pragma unroll
    for (int j = 0; j < 4; ++j) acc[i][j] = 0.f;
  for (int ks = 0; ks < 8; ++ks) {
    int k0 = ks * 48;
    for (int i = tid; i < 64 * 12; i += 192) {
      int row = i % 64, cg = i / 64;
      float4 v = *(const float4*)(hb + ((size_t)(g0 + row)) * 384 + k0 + 4 * cg);
      float* d = &At[(4 * cg) * 66 + row];
      d[0] = v.x; d[66] = v.y; d[132] = v.z; d[198] = v.w;
    }
    for (int i = tid; i < 48 * 12; i += 192) {
      int row = i % 48, cg = i / 48;
      float4 v = *(const float4*)(w2 + ((size_t)(nt * 48 + row)) * 384 + k0 + 4 * cg);
      float* d = &Wt[(4 * cg) * 50 + row];
      d[0] = v.x; d[50] = v.y; d[100] = v.z; d[150] = v.w;
    }
    __syncthreads();
    mm48<4, 4>(At, Wt, 66, 50, r0, j0, acc);
    __syncthreads();
  }
  int jg = nt * 48 + j0;
  // write through LDS transpose for coalesced global stores
  __syncthreads();
#pragma unroll
  for (int i = 0; i < 4; ++i) {
    int r = r0 + i;
#pragma unroll
    for (int j = 0; j < 4; ++j) {
      float v = acc[i][j] + b2[jg + j] + xr[((size_t)(g0 + r)) * 96 + jg + j];
      At[(j0 + j) * 68 + r] = v;
    }
  }
  __syncthreads();
  for (int i = tid; i < 48 * 16; i += 192) {
    int cc = i / 16, sq = i % 16;
    float4 v = *(const float4*)&At[cc * 68 + 4 * sq];
    int ccg = nt * 48 + cc;
    *(float4*)&out[((size_t)b * 96 + ccg) * L_ + s0 + 4 * sq] = v;
  }
}

extern "C" void kernel_launch(void* const* d_in, const int* in_sizes, int n_in,
                              void* d_out, int out_size, void* d_ws, size_t ws_size,
                              hipStream_t stream) {
  const float* x       = (const float*)d_in[0];
  const float* norm_g  = (const float*)d_in[1];
  const float* norm_b  = (const float*)d_in[2];
  const float* in_w    = (const float*)d_in[3];
  const float* conv_w  = (const float*)d_in[4];
  const float* conv_b  = (const float*)d_in[5];
  const float* xproj_w = (const float*)d_in[6];
  const float* dt_w    = (const float*)d_in[7];
  const float* dt_b    = (const float*)d_in[8];
  const float* A_log   = (const float*)d_in[9];
  const float* Dp      = (const float*)d_in[10];
  const float* out_w   = (const float*)d_in[11];
  const float* merge_w = (const float*)d_in[12];
  const float* merge_b = (const float*)d_in[13];
  const float* ffn_g   = (const float*)d_in[14];
  const float* ffn_be  = (const float*)d_in[15];
  const float* ffn_w1  = (const float*)d_in[16];
  const float* ffn_b1  = (const float*)d_in[17];
  const float* ffn_w2  = (const float*)d_in[18];
  const float* ffn_b2  = (const float*)d_in[19];
  float* out = (float*)d_out;

  // workspace layout (floats). total = 30,343,168 floats = 121.4 MB
  float* ws = (float*)d_ws;
  size_t o = 0;
  float* xn  = ws + o; o += (size_t)B_ * L_ * C_;               // 786,432
  float* Wf  = ws + o; o += (size_t)ND_ * 256 * 192;            // 196,608
  float* xsr = ws + o; o += (size_t)ND_ * B_ * L_ * DI_;        // 6,291,456 (-> gb)
  float* zb  = ws + o; o += (size_t)ND_ * B_ * L_ * DI_;        // 6,291,456 (-> hb)
  float* xs  = ws + o; o += (size_t)ND_ * B_ * L_ * DI_;        // 6,291,456 (-> nrm)
  float* xbc = ws + o; o += (size_t)ND_ * B_ * L_ * 32;         // 1,048,576
  float* dlt = ws + o; o += (size_t)ND_ * B_ * L_ * DI_;        // 6,291,456 (-> yo, xr)
  float* Pb  = ws + o; o += (size_t)ND_ * B_ * NC_ * DI_ * DS_; // 1,572,864
  float* Sb  = ws + o; o += (size_t)ND_ * B_ * NC_ * DI_ * DS_; // 1,572,864
  // stream-ordered aliases:
  float* gb  = xsr;
  float* yo  = dlt;
  float* xr  = dlt + (size_t)ND_ * B_ * L_ * C_;
  float* nrm = xs;
  float* hb  = zb;

  k_ln     <<<B_ * 64, 256, 0, stream>>>(x, norm_g, norm_b, xn);
  k_prep   <<<ND_ * 256 * 192 / 256, 256, 0, stream>>>(dt_w, xproj_w, Wf);
  k_inproj <<<ND_ * B_ * 32 * 6, 128, 0, stream>>>(xn, in_w, xsr, zb);
  k_conv   <<<(ND_ * B_ * L_ * DI_) / 256, 256, 0, stream>>>(xsr, conv_w, conv_b, xs);
  k_dgemm  <<<ND_ * B_ * 32 * 4, 128, 0, stream>>>(xs, Wf, dt_b, dlt, xbc);
  k_scan1  <<<ND_ * B_ * NC_, DI_, 0, stream>>>(dlt, xs, xbc, A_log, Pb, Sb);
  k_scan2  <<<(ND_ * B_ * DI_ * DS_) / 256, 256, 0, stream>>>(Pb, Sb);
  k_scan3  <<<ND_ * B_ * NC_, DI_, 0, stream>>>(dlt, xs, xbc, A_log, Sb, Dp, zb, gb);
  k_outproj<<<ND_ * B_ * 32, 192, 0, stream>>>(gb, out_w, yo);
  k_merge  <<<B_ * 64 * 2, 192, 0, stream>>>(yo, merge_w, merge_b, x, xr);
  k_ln2    <<<(B_ * L_) / 64, 256, 0, stream>>>(xr, ffn_g, ffn_be, nrm);
  k_ffn1   <<<(B_ * L_ / 128) * 6, 128, 0, stream>>>(nrm, ffn_w1, ffn_b1, hb);
  k_ffn2   <<<(B_ * L_ / 64) * 2, 192, 0, stream>>>(hb, ffn_w2, ffn_b2, xr, out);
}

// Round 3
// 362.246 us; speedup vs baseline: 4.1905x; 1.6832x over previous
//
#include <hip/hip_runtime.h>

#define B_ 2
#define C_ 96
#define L_ 4096
#define DI_ 192
#define DS_ 16
#define DTR_ 6
#define ND_ 4
#define CH_ 32
#define NC_ 128

typedef float f32x4 __attribute__((ext_vector_type(4)));
typedef short bf16x8 __attribute__((ext_vector_type(8)));

// direction map: sequence position l -> spatial index s (row-major h*W+w). Involution.
__device__ __forceinline__ int smap(int k, int l) {
  if (k == 0) return l;
  if (k == 1) return L_ - 1 - l;
  if (k == 2) return ((l & 63) << 6) | (l >> 6);
  int l2 = L_ - 1 - l;
  return ((l2 & 63) << 6) | (l2 >> 6);
}

__device__ __forceinline__ float sp_softplus(float v) {
  return fmaxf(v, 0.f) + log1pf(expf(-fabsf(v)));
}
__device__ __forceinline__ float silu(float v) { return v / (1.f + expf(-v)); }
__device__ __forceinline__ float gelu(float v) {
  return 0.5f * v * (1.f + erff(v * 0.70710678118654752f));
}
__device__ __forceinline__ ushort f2bf(float f) {
  unsigned u = __float_as_uint(f);
  return (ushort)((u + 0x7FFFu + ((u >> 16) & 1u)) >> 16);  // RNE
}
__device__ __forceinline__ float bf2f(ushort u) {
  return __uint_as_float(((unsigned)u) << 16);
}

// ============ K1: LayerNorm over C (coalesced), x(B,C,L) -> xn bf16 (B,L,C) ============
__global__ __launch_bounds__(256) void k_ln(const float* __restrict__ x, const float* __restrict__ g,
                                            const float* __restrict__ bt, ushort* __restrict__ xn) {
  int b = blockIdx.x / 64;
  int s0 = (blockIdx.x % 64) * 64;
  int tid = threadIdx.x;
  __shared__ float X[96 * 65];
  __shared__ float Ms[64], Rs[64];
  for (int i = tid; i < 96 * 64; i += 256) {
    int c = i / 64, ls = i % 64;
    X[c * 65 + ls] = x[((size_t)b * 96 + c) * L_ + s0 + ls];
  }
  __syncthreads();
  {
    int ls = tid >> 2, q = tid & 3;
    float s1 = 0.f, s2 = 0.f;
    for (int c = q; c < 96; c += 4) {
      float v = X[c * 65 + ls];
      s1 += v; s2 += v * v;
    }
    s1 += __shfl_xor(s1, 1); s1 += __shfl_xor(s1, 2);
    s2 += __shfl_xor(s2, 1); s2 += __shfl_xor(s2, 2);
    if (q == 0) {
      float m = s1 * (1.f / 96.f);
      Ms[ls] = m;
      Rs[ls] = rsqrtf(s2 * (1.f / 96.f) - m * m + 1e-5f);
    }
  }
  __syncthreads();
  for (int i = tid; i < 96 * 64; i += 256) {
    int c = i % 96, ls = i / 96;
    float v = (X[c * 65 + ls] - Ms[ls]) * Rs[ls] * g[c] + bt[c];
    xn[((size_t)b * L_ + s0 + ls) * 96 + c] = f2bf(v);
  }
}

// ============ K2: convert/build all bf16 weights ============
// segments (ushort counts): in_wb 147456 | Wf 172032 (4 x 224 x 192) | out_wb 73728 |
// merge_wb 36864 | w1b 36864 | w2b 36864   (total 503808 = 1968*256)
__global__ void k_prep(const float* __restrict__ in_w, const float* __restrict__ dt_w,
                       const float* __restrict__ xproj_w, const float* __restrict__ out_w,
                       const float* __restrict__ merge_w, const float* __restrict__ w1,
                       const float* __restrict__ w2, ushort* __restrict__ wb) {
  int idx = blockIdx.x * 256 + threadIdx.x;
  if (idx < 147456) { wb[idx] = f2bf(in_w[idx]); return; }
  int i1 = idx - 147456;
  if (i1 < 172032) {
    int k = i1 / 43008, r = i1 % 43008;
    int j = r / 192, i = r % 192;
    float v;
    if (j < 192) {
      v = 0.f;
#pragma unroll
      for (int r6 = 0; r6 < DTR_; ++r6)
        v += dt_w[((size_t)k * 192 + j) * DTR_ + r6] * xproj_w[((size_t)k * 38 + r6) * 192 + i];
    } else {
      v = xproj_w[((size_t)k * 38 + 6 + (j - 192)) * 192 + i];
    }
    wb[idx] = f2bf(v);
    return;
  }
  int i2 = i1 - 172032;
  if (i2 < 73728) { wb[idx] = f2bf(out_w[i2]); return; }
  int i3 = i2 - 73728;
  if (i3 < 36864) { wb[idx] = f2bf(merge_w[i3]); return; }
  int i4 = i3 - 36864;
  if (i4 < 36864) { wb[idx] = f2bf(w1[i4]); return; }
  int i5 = i4 - 36864;
  wb[idx] = f2bf(w2[i5]);
}

// ============ generic MFMA GEMM ============
// MODE 0: inproj   A=xn bf16 gather(smap), K=96,  NBLK=4(NT96) -> xsr/zb fp32
// MODE 1: dgemm    A=xsb,                  K=192, NBLK=2(NT112)-> dlt fp32(softplus+dt_b)/xbc fp32
// MODE 2: outproj  A=gb,                   K=192, NBLK=1(NT96) -> yo bf16
// MODE 3: merge    A=yo gather(smap/seg),  K=384, NBLK=1(NT96) -> xr fp32 (+mb +x residual)
// MODE 4: ffn1     A=nrm,                  K=96,  NBLK=4(NT96) -> hb bf16 (gelu+b1)
// MODE 5: ffn2     A=hb,                   K=384, NBLK=1(NT96) -> out fp32 transposed (+b2 +xr)
template <int MODE, int KTOT, int NF, int NBLK>
__global__ __launch_bounds__(256) void k_mm(const ushort* __restrict__ A, const ushort* __restrict__ W,
                                            const float* __restrict__ bias, const float* __restrict__ res,
                                            float* __restrict__ o0, float* __restrict__ o1,
                                            ushort* __restrict__ ob) {
  int tid = threadIdx.x, lane = tid & 63, wv = tid >> 6;
  int bx = blockIdx.x;
  int nb = bx % NBLK, mb = bx / NBLK;
  int n0 = nb * NF * 16;
  int kb = 0, b = 0, kd = 0, s0 = 0;
  if (MODE == 0) { kb = mb >> 5; kd = kb >> 1; b = kb & 1; s0 = (mb & 31) * 128; }
  if (MODE == 3) { b = mb >> 5; s0 = (mb & 31) * 128; }
  size_t gm0 = (size_t)mb * 128;

  __shared__ __align__(16) ushort At[128 * 104];
  f32x4 acc[2][NF];
#pragma unroll
  for (int mf = 0; mf < 2; ++mf)
#pragma unroll
    for (int n = 0; n < NF; ++n) acc[mf][n] = (f32x4){0.f, 0.f, 0.f, 0.f};

#pragma unroll
  for (int kt = 0; kt < KTOT / 96; ++kt) {
    const int k0 = kt * 96;
    for (int i = tid; i < 128 * 12; i += 256) {
      int row = i / 12, c = i % 12;
      const ushort* src;
      if (MODE == 0)      src = A + ((size_t)b * L_ + smap(kd, s0 + row)) * 96 + c * 8;
      else if (MODE == 3) src = A + (((size_t)kt * B_ + b) * L_ + smap(kt, s0 + row)) * 96 + c * 8;
      else                src = A + (gm0 + row) * KTOT + k0 + c * 8;
      *(uint4*)(void*)&At[row * 104 + c * 8] = *(const uint4*)(const void*)src;
    }
    __syncthreads();
#pragma unroll
    for (int kk = 0; kk < 3; ++kk) {
      bf16x8 bfr[NF];
#pragma unroll
      for (int n = 0; n < NF; ++n)
        bfr[n] = *(const bf16x8*)(const void*)(W + (size_t)(n0 + n * 16 + (lane & 15)) * KTOT +
                                               k0 + kk * 32 + (lane >> 4) * 8);
#pragma unroll
      for (int mf = 0; mf < 2; ++mf) {
        bf16x8 afr = *(const bf16x8*)(void*)&At[(wv * 32 + mf * 16 + (lane & 15)) * 104 +
                                                kk * 32 + (lane >> 4) * 8];
#pragma unroll
        for (int n = 0; n < NF; ++n)
          acc[mf][n] = __builtin_amdgcn_mfma_f32_16x16x32_bf16(afr, bfr[n], acc[mf][n], 0, 0, 0);
      }
    }
    __syncthreads();
  }

  int col = lane & 15, rq = lane >> 4;
#pragma unroll
  for (int mf = 0; mf < 2; ++mf) {
    int rl = wv * 32 + mf * 16 + rq * 4;
#pragma unroll
    for (int n = 0; n < NF; ++n) {
      int j = n0 + n * 16 + col;
      if (MODE == 0) {
        size_t rb = (size_t)kb * L_ + s0 + rl;
#pragma unroll
        for (int v = 0; v < 4; ++v) {
          float val = acc[mf][n][v];
          size_t ro = (rb + v) * 192;
          if (j < 192) o0[ro + j] = val;
          else o1[ro + j - 192] = val;
        }
      } else if (MODE == 1) {
        int kdl = (int)(mb >> 6);
#pragma unroll
        for (int v = 0; v < 4; ++v) {
          float val = acc[mf][n][v];
          size_t ro = gm0 + rl + v;
          if (j < 192) o0[ro * 192 + j] = sp_softplus(val + bias[kdl * 192 + j]);
          else o1[ro * 32 + (j - 192)] = val;
        }
      } else if (MODE == 2) {
#pragma unroll
        for (int v = 0; v < 4; ++v) ob[(gm0 + rl + v) * 96 + j] = f2bf(acc[mf][n][v]);
      } else if (MODE == 3) {
        float4 rv = *(const float4*)&res[((size_t)b * 96 + j) * L_ + s0 + rl];
#pragma unroll
        for (int v = 0; v < 4; ++v)
          o0[((size_t)b * L_ + s0 + rl + v) * 96 + j] = acc[mf][n][v] + bias[j] + (&rv.x)[v];
      } else if (MODE == 4) {
#pragma unroll
        for (int v = 0; v < 4; ++v)
          ob[(gm0 + rl + v) * 384 + j] = f2bf(gelu(acc[mf][n][v] + bias[j]));
      } else {
        int bb = (int)(gm0 >> 12);
        int sl = (int)(gm0 & 4095) + rl;
        float4 o;
#pragma unroll
        for (int v = 0; v < 4; ++v)
          (&o.x)[v] = acc[mf][n][v] + bias[j] + res[((size_t)bb * L_ + sl + v) * 96 + j];
        *(float4*)&o0[((size_t)bb * 96 + j) * L_ + sl] = o;
      }
    }
  }
}

// ============ K4: causal depthwise conv (k=4) + silu -> xs bf16 ============
__global__ void k_conv(const float* __restrict__ xsr, const float* __restrict__ cw,
                       const float* __restrict__ cb, ushort* __restrict__ xsb) {
  int idx = blockIdx.x * blockDim.x + threadIdx.x;
  int d = idx % DI_;
  int rest = idx / DI_;
  int l = rest % L_;
  int kb = rest / L_;
  int k = kb / B_;
  float acc = cb[k * DI_ + d];
  const float* w = cw + ((size_t)k * DI_ + d) * 4;
#pragma unroll
  for (int j = 0; j < 4; ++j) {
    int t = l - 3 + j;
    if (t >= 0) acc += xsr[((size_t)kb * L_ + t) * DI_ + d] * w[j];
  }
  xsb[idx] = f2bf(silu(acc));
}

// ============ K6: scan phase 1 (chunks of 32) ============
__global__ void k_scan1(const float* __restrict__ dlt, const ushort* __restrict__ xsb,
                        const float* __restrict__ xbc, const float* __restrict__ A_log,
                        float* __restrict__ Pb, float* __restrict__ Sb) {
  int blk = blockIdx.x;
  int c = blk % NC_;
  int kb = blk / NC_;
  int k = kb / B_;
  int d = threadIdx.x;  // 192
  __shared__ float Bs[CH_][DS_];
  for (int i = threadIdx.x; i < CH_ * DS_; i += DI_) {
    int t = i / DS_, n = i % DS_;
    Bs[t][n] = xbc[((size_t)kb * L_ + c * CH_ + t) * 32 + n];
  }
  float A2[DS_];
  const float* al = A_log + ((size_t)k * DI_ + d) * DS_;
#pragma unroll
  for (int n = 0; n < DS_; ++n) A2[n] = -expf(al[n]) * 1.4426950408889634f;
  __syncthreads();
  float h[DS_];
#pragma unroll
  for (int n = 0; n < DS_; ++n) h[n] = 0.f;
  float sumd = 0.f;
  const size_t rowb = ((size_t)kb * L_ + c * CH_) * DI_ + d;
  for (int t = 0; t < CH_; ++t) {
    float de = dlt[rowb + (size_t)t * DI_];
    float xv = bf2f(xsb[rowb + (size_t)t * DI_]);
    float dx = de * xv;
    sumd += de;
#pragma unroll
    for (int n = 0; n < DS_; ++n)
      h[n] = fmaf(exp2f(A2[n] * de), h[n], dx * Bs[t][n]);
  }
  size_t base = (((size_t)kb * NC_ + c) * DI_ + d) * DS_;
#pragma unroll
  for (int n = 0; n < DS_; ++n) {
    Pb[base + n] = exp2f(A2[n] * sumd);
    Sb[base + n] = h[n];
  }
}

// ============ K7: scan phase 2 — serial chunk combine ============
__global__ void k_scan2(const float* __restrict__ Pb, float* __restrict__ Sb) {
  int gid = blockIdx.x * blockDim.x + threadIdx.x;  // ND*B*DI*DS = 24576
  int dn = gid % (DI_ * DS_);
  int kb = gid / (DI_ * DS_);
  size_t base = (size_t)kb * NC_ * DI_ * DS_ + dn;
  float h = 0.f;
  for (int c = 0; c < NC_; ++c) {
    size_t i = base + (size_t)c * DI_ * DS_;
    float p = Pb[i], s = Sb[i];
    Sb[i] = h;
    h = fmaf(p, h, s);
  }
}

// ============ K8: scan phase 3 — fused y=(scan+xs*D)*silu(z) -> gb bf16 ============
__global__ void k_scan3(const float* __restrict__ dlt, const ushort* __restrict__ xsb,
                        const float* __restrict__ xbc, const float* __restrict__ A_log,
                        const float* __restrict__ hin, const float* __restrict__ Dpp,
                        const float* __restrict__ zb, ushort* __restrict__ gb) {
  int blk = blockIdx.x;
  int c = blk % NC_;
  int kb = blk / NC_;
  int k = kb / B_;
  int d = threadIdx.x;  // 192
  __shared__ float Bs[CH_][DS_], Cs[CH_][DS_];
  for (int i = threadIdx.x; i < CH_ * DS_; i += DI_) {
    int t = i / DS_, n = i % DS_;
    size_t rb = ((size_t)kb * L_ + c * CH_ + t) * 32;
    Bs[t][n] = xbc[rb + n];
    Cs[t][n] = xbc[rb + 16 + n];
  }
  float A2[DS_];
  const float* al = A_log + ((size_t)k * DI_ + d) * DS_;
#pragma unroll
  for (int n = 0; n < DS_; ++n) A2[n] = -expf(al[n]) * 1.4426950408889634f;
  float h[DS_];
  size_t hbase = (((size_t)kb * NC_ + c) * DI_ + d) * DS_;
#pragma unroll
  for (int n = 0; n < DS_; ++n) h[n] = hin[hbase + n];
  float Dv = Dpp[k * DI_ + d];
  __syncthreads();
  const size_t rowb = ((size_t)kb * L_ + c * CH_) * DI_ + d;
  for (int t = 0; t < CH_; ++t) {
    float de = dlt[rowb + (size_t)t * DI_];
    float xv = bf2f(xsb[rowb + (size_t)t * DI_]);
    float dx = de * xv;
    float acc = 0.f;
#pragma unroll
    for (int n = 0; n < DS_; ++n) {
      h[n] = fmaf(exp2f(A2[n] * de), h[n], dx * Bs[t][n]);
      acc = fmaf(h[n], Cs[t][n], acc);
    }
    float y = acc + xv * Dv;
    float zv = zb[rowb + (size_t)t * DI_];
    gb[rowb + (size_t)t * DI_] = f2bf(y * silu(zv));
  }
}

// ============ K11: second LayerNorm: xr fp32 -> nrm bf16 ============
__global__ __launch_bounds__(256) void k_ln2(const float* __restrict__ xr, const float* __restrict__ fg,
                                             const float* __restrict__ fb, ushort* __restrict__ nrm) {
  int g0 = blockIdx.x * 64;
  int r = threadIdx.x / 4, q = threadIdx.x & 3;
  const float* src = xr + ((size_t)(g0 + r)) * 96 + q * 24;
  float4 v[6];
  float s1 = 0.f, s2 = 0.f;
#pragma unroll
  for (int e = 0; e < 6; ++e) {
    v[e] = *(const float4*)(src + 4 * e);
    s1 += v[e].x + v[e].y + v[e].z + v[e].w;
    s2 += v[e].x * v[e].x + v[e].y * v[e].y + v[e].z * v[e].z + v[e].w * v[e].w;
  }
  s1 += __shfl_xor(s1, 1); s1 += __shfl_xor(s1, 2);
  s2 += __shfl_xor(s2, 1); s2 += __shfl_xor(s2, 2);
  float m = s1 * (1.f / 96.f);
  float rstd = rsqrtf(s2 * (1.f / 96.f) - m * m + 1e-5f);
  ushort* dst = nrm + ((size_t)(g0 + r)) * 96 + q * 24;
#pragma unroll
  for (int e = 0; e < 6; ++e) {
    int c = q * 24 + 4 * e;
    ushort4 o;
    o.x = f2bf((v[e].x - m) * rstd * fg[c] + fb[c]);
    o.y = f2bf((v[e].y - m) * rstd * fg[c + 1] + fb[c + 1]);
    o.z = f2bf((v[e].z - m) * rstd * fg[c + 2] + fb[c + 2]);
    o.w = f2bf((v[e].w - m) * rstd * fg[c + 3] + fb[c + 3]);
    *(ushort4*)(dst + 4 * e) = o;
  }
}

extern "C" void kernel_launch(void* const* d_in, const int* in_sizes, int n_in,
                              void* d_out, int out_size, void* d_ws, size_t ws_size,
                              hipStream_t stream) {
  const float* x       = (const float*)d_in[0];
  const float* norm_g  = (const float*)d_in[1];
  const float* norm_b  = (const float*)d_in[2];
  const float* in_w    = (const float*)d_in[3];
  const float* conv_w  = (const float*)d_in[4];
  const float* conv_b  = (const float*)d_in[5];
  const float* xproj_w = (const float*)d_in[6];
  const float* dt_w    = (const float*)d_in[7];
  const float* dt_b    = (const float*)d_in[8];
  const float* A_log   = (const float*)d_in[9];
  const float* Dp      = (const float*)d_in[10];
  const float* out_w   = (const float*)d_in[11];
  const float* merge_w = (const float*)d_in[12];
  const float* merge_b = (const float*)d_in[13];
  const float* ffn_g   = (const float*)d_in[14];
  const float* ffn_be  = (const float*)d_in[15];
  const float* ffn_w1  = (const float*)d_in[16];
  const float* ffn_b1  = (const float*)d_in[17];
  const float* ffn_w2  = (const float*)d_in[18];
  const float* ffn_b2  = (const float*)d_in[19];
  float* out = (float*)d_out;

  // workspace layout (float units). total = 30,005,248 floats = 120.0 MB
  float* ws = (float*)d_ws;
  ushort* xnb = (ushort*)(ws + 0);             // B*L*96 u        (393216 f)
  ushort* wbu = (ushort*)(ws + 393216);        // 503808 u        (251904 f)
  float*  xsr = ws + 645120;                   // ND*B*L*192 f
  float*  zb  = ws + 6936576;                  // ND*B*L*192 f (-> xr | nrm | hb)
  ushort* xsb = (ushort*)(ws + 13228032);      // ND*B*L*192 u    (3145728 f)
  float*  dlt = ws + 16373760;                 // ND*B*L*192 f
  float*  xbc = ws + 22665216;                 // ND*B*L*32 f
  float*  Pb  = ws + 23713792;                 // ND*B*NC*192*16 f
  float*  Sb  = ws + 26859520;                 // same
  // weight sub-pointers (ushort units from wbu)
  ushort* in_wb    = wbu;
  ushort* Wf       = wbu + 147456;
  ushort* out_wb   = wbu + 319488;
  ushort* merge_wb = wbu + 393216;
  ushort* w1b      = wbu + 430080;
  ushort* w2b      = wbu + 466944;
  // stream-ordered aliases
  ushort* gbu  = (ushort*)xsr;                 // ND*B*L*192 u (after conv consumed xsr)
  ushort* you  = (ushort*)(xsr + 3145728);     // ND*B*L*96 u
  float*  xr   = zb;                           // B*L*96 f (after scan3 consumed zb)
  ushort* nrmu = (ushort*)(zb + 786432);       // B*L*96 u
  ushort* hbu  = (ushort*)(zb + 1179648);      // B*L*384 u

  k_ln   <<<B_ * 64, 256, 0, stream>>>(x, norm_g, norm_b, xnb);
  k_prep <<<1968, 256, 0, stream>>>(in_w, dt_w, xproj_w, out_w, merge_w, ffn_w1, ffn_w2, wbu);
  k_mm<0, 96, 6, 4><<<1024, 256, 0, stream>>>(xnb, in_wb, nullptr, nullptr, xsr, zb, nullptr);
  k_conv <<<(ND_ * B_ * L_ * DI_) / 256, 256, 0, stream>>>(xsr, conv_w, conv_b, xsb);
  k_mm<1, 192, 7, 2><<<512, 256, 0, stream>>>(xsb, Wf, dt_b, nullptr, dlt, xbc, nullptr);
  k_scan1<<<ND_ * B_ * NC_, DI_, 0, stream>>>(dlt, xsb, xbc, A_log, Pb, Sb);
  k_scan2<<<(ND_ * B_ * DI_ * DS_) / 256, 256, 0, stream>>>(Pb, Sb);
  k_scan3<<<ND_ * B_ * NC_, DI_, 0, stream>>>(dlt, xsb, xbc, A_log, Sb, Dp, zb, gbu);
  k_mm<2, 192, 6, 1><<<256, 256, 0, stream>>>(gbu, out_wb, nullptr, nullptr, nullptr, nullptr, you);
  k_mm<3, 384, 6, 1><<<64, 256, 0, stream>>>(you, merge_wb, merge_b, x, xr, nullptr, nullptr);
  k_ln2  <<<(B_ * L_) / 64, 256, 0, stream>>>(xr, ffn_g, ffn_be, nrmu);
  k_mm<4, 96, 6, 4><<<256, 256, 0, stream>>>(nrmu, w1b, ffn_b1, nullptr, nullptr, nullptr, hbu);
  k_mm<5, 384, 6, 1><<<64, 256, 0, stream>>>(hbu, w2b, ffn_b2, xr, out, nullptr, nullptr);
}

// Round 5
// 345.883 us; speedup vs baseline: 4.3888x; 1.0473x over previous
//
#include <hip/hip_runtime.h>

#define B_ 2
#define C_ 96
#define L_ 4096
#define DI_ 192
#define DS_ 16
#define DTR_ 6
#define ND_ 4
#define CH_ 32
#define NC_ 128

typedef float f32x4 __attribute__((ext_vector_type(4)));
typedef short bf16x8 __attribute__((ext_vector_type(8)));

// direction map: sequence position l -> spatial index s (row-major h*W+w). Involution.
__device__ __forceinline__ int smap(int k, int l) {
  if (k == 0) return l;
  if (k == 1) return L_ - 1 - l;
  if (k == 2) return ((l & 63) << 6) | (l >> 6);
  int l2 = L_ - 1 - l;
  return ((l2 & 63) << 6) | (l2 >> 6);
}

__device__ __forceinline__ float sp_softplus(float v) {
  return fmaxf(v, 0.f) + log1pf(expf(-fabsf(v)));
}
__device__ __forceinline__ float silu(float v) { return v / (1.f + expf(-v)); }
__device__ __forceinline__ float gelu(float v) {
  return 0.5f * v * (1.f + erff(v * 0.70710678118654752f));
}
__device__ __forceinline__ ushort f2bf(float f) {
  unsigned u = __float_as_uint(f);
  return (ushort)((u + 0x7FFFu + ((u >> 16) & 1u)) >> 16);  // RNE
}
__device__ __forceinline__ float bf2f(ushort u) {
  return __uint_as_float(((unsigned)u) << 16);
}

// ============ K1: LayerNorm over C (coalesced), x(B,C,L) -> xn bf16 (B,L,C) ============
__global__ __launch_bounds__(256) void k_ln(const float* __restrict__ x, const float* __restrict__ g,
                                            const float* __restrict__ bt, ushort* __restrict__ xn) {
  int b = blockIdx.x / 64;
  int s0 = (blockIdx.x % 64) * 64;
  int tid = threadIdx.x;
  __shared__ float X[96 * 65];
  __shared__ float Ms[64], Rs[64];
  for (int i = tid; i < 96 * 64; i += 256) {
    int c = i / 64, ls = i % 64;
    X[c * 65 + ls] = x[((size_t)b * 96 + c) * L_ + s0 + ls];
  }
  __syncthreads();
  {
    int ls = tid >> 2, q = tid & 3;
    float s1 = 0.f, s2 = 0.f;
    for (int c = q; c < 96; c += 4) {
      float v = X[c * 65 + ls];
      s1 += v; s2 += v * v;
    }
    s1 += __shfl_xor(s1, 1); s1 += __shfl_xor(s1, 2);
    s2 += __shfl_xor(s2, 1); s2 += __shfl_xor(s2, 2);
    if (q == 0) {
      float m = s1 * (1.f / 96.f);
      Ms[ls] = m;
      Rs[ls] = rsqrtf(s2 * (1.f / 96.f) - m * m + 1e-5f);
    }
  }
  __syncthreads();
  for (int i = tid; i < 96 * 64; i += 256) {
    int c = i % 96, ls = i / 96;
    float v = (X[c * 65 + ls] - Ms[ls]) * Rs[ls] * g[c] + bt[c];
    xn[((size_t)b * L_ + s0 + ls) * 96 + c] = f2bf(v);
  }
}

// ============ K2a: elementwise weight converts / Wf build ============
// bundle (ushort offsets): in_wb@0 (147456) | Wf@147456 (4x256x192=196608) |
// W1p@344064 (36864) | w2b@380928 (36864) | Wkm@417792 (73728, filled by k_prepm)
__global__ void k_prepw(const float* __restrict__ in_w, const float* __restrict__ dt_w,
                        const float* __restrict__ xproj_w, const float* __restrict__ w1,
                        const float* __restrict__ g, const float* __restrict__ w2,
                        ushort* __restrict__ wb) {
  int idx = blockIdx.x * 256 + threadIdx.x;
  if (idx >= 417792) return;
  if (idx < 147456) { wb[idx] = f2bf(in_w[idx]); return; }
  int i1 = idx - 147456;
  if (i1 < 196608) {  // Wf: rows<192: dt_w @ xproj_w[:6]; rows 192..223: B/C rows; 224..255: 0
    int k = i1 / 49152, r = i1 % 49152;
    int j = r / 192, i = r % 192;
    float v = 0.f;
    if (j < 192) {
#pragma unroll
      for (int r6 = 0; r6 < DTR_; ++r6)
        v += dt_w[((size_t)k * 192 + j) * DTR_ + r6] * xproj_w[((size_t)k * 38 + r6) * 192 + i];
    } else if (j < 224) {
      v = xproj_w[((size_t)k * 38 + 6 + (j - 192)) * 192 + i];
    }
    wb[idx] = f2bf(v);
    return;
  }
  int i2 = i1 - 196608;
  if (i2 < 36864) {  // W1p = w1 * g (per input col)
    wb[idx] = f2bf(w1[i2] * g[i2 % 96]);
    return;
  }
  int i3 = i2 - 36864;
  wb[idx] = f2bf(w2[i3]);
}

// ============ K2b: fused out_w x merge_w weight + LN-folding vectors ============
__global__ void k_prepm(const float* __restrict__ merge_w, const float* __restrict__ out_w,
                        const float* __restrict__ w1, const float* __restrict__ g,
                        const float* __restrict__ be, const float* __restrict__ b1,
                        ushort* __restrict__ wkm, float* __restrict__ ug, float* __restrict__ vb) {
  int idx = blockIdx.x * 256 + threadIdx.x;
  if (idx < 73728) {  // Wkm[k][j][i] = sum_c merge_w[j][k*96+c] * out_w[k][c][i]
    int k = idx / 18432, r = idx % 18432;
    int j = r / 192, i = r % 192;
    float v = 0.f;
    for (int c = 0; c < 96; ++c)
      v += merge_w[(size_t)j * 384 + k * 96 + c] * out_w[((size_t)k * 96 + c) * 192 + i];
    wkm[idx] = f2bf(v);
  } else if (idx < 74496) {
    int t = idx - 73728;
    int j = t % 384;
    float s = 0.f;
    if (t < 384) {
      for (int c = 0; c < 96; ++c) s += g[c] * w1[(size_t)j * 96 + c];
      ug[j] = s;
    } else {
      for (int c = 0; c < 96; ++c) s += be[c] * w1[(size_t)j * 96 + c];
      vb[j] = s + b1[j];
    }
  }
}

// ============ unified MFMA GEMM, A and W tiles both LDS-staged ============
// MODE 0 inproj:   A=xn gather(smap), K=96,  NBLK=4 NT96, MT128 -> xsrb/zbb bf16
// MODE 1 dgemm:    A=xsb,             K=192, NBLK=2 NT128,MT128 -> dlt fp32(softplus)/xbc fp32
// MODE 2 outmerge: A=gb gather, per-dir split, K=192, NT96, MT64 -> pout fp32 [4][8192][96]
// MODE 3 ffn1:     A=xrb, K=96, NBLK=4 NT96, MT64 -> hb bf16 (LN-folded + gelu)
// MODE 4 ffn2:     A=hb, K-split2 (192 each), NT96, MT64 -> pffn fp32 [2][8192][96]
template <int MODE, int KBLK, int NFR, int NBLK, int MT>
__global__ __launch_bounds__(256) void k_gemm(
    const ushort* __restrict__ A, const ushort* __restrict__ W,
    const float* __restrict__ f0, const float* __restrict__ f1,
    const float* __restrict__ f2, const float* __restrict__ f3,
    float* __restrict__ g0, float* __restrict__ g1,
    ushort* __restrict__ u0, ushort* __restrict__ u1) {
  constexpr int NT = NFR * 32;
  constexpr int MF = MT / 32;
  int tid = threadIdx.x, lane = tid & 63;
  int wvm = tid >> 7, wvn = (tid >> 6) & 1;
  int bx = blockIdx.x;
  int nb = 0, mb = 0, kd = 0, b = 0, s0 = 0, sp = 0;
  if (MODE == 0) { nb = bx & 3; mb = bx >> 2; }
  if (MODE == 1) { nb = bx & 1; mb = bx >> 1; }
  if (MODE == 2) { kd = bx >> 7; mb = bx & 127; }
  if (MODE == 3) { nb = bx & 3; mb = bx >> 2; }
  if (MODE == 4) { sp = bx >> 7; mb = bx & 127; }
  size_t gm0 = (size_t)mb * MT;
  if (MODE == 0) { kd = (int)(gm0 >> 13); b = (int)((gm0 >> 12) & 1); s0 = (int)(gm0 & 4095); }
  if (MODE == 1) { kd = (int)(gm0 >> 13); }
  if (MODE == 2) { b = (int)(gm0 >> 12); s0 = (int)(gm0 & 4095); }

  __shared__ __align__(16) ushort At[MT * 104];
  __shared__ __align__(16) ushort Wt[NT * 104];

  f32x4 acc[MF][NFR];
#pragma unroll
  for (int m = 0; m < MF; ++m)
#pragma unroll
    for (int n = 0; n < NFR; ++n) acc[m][n] = (f32x4){0.f, 0.f, 0.f, 0.f};

#pragma unroll
  for (int kt = 0; kt < KBLK / 96; ++kt) {
    const int k0 = kt * 96;
    for (int i = tid; i < MT * 12; i += 256) {
      int row = i / 12, c = i % 12;
      const ushort* src;
      if (MODE == 0)      src = A + ((size_t)b * L_ + smap(kd, s0 + row)) * 96 + c * 8;
      else if (MODE == 2) src = A + (((size_t)kd * B_ + b) * L_ + smap(kd, s0 + row)) * 192 + k0 + c * 8;
      else if (MODE == 1) src = A + (gm0 + row) * 192 + k0 + c * 8;
      else if (MODE == 3) src = A + (gm0 + row) * 96 + c * 8;
      else                src = A + (gm0 + row) * 384 + sp * 192 + k0 + c * 8;
      *(uint4*)(void*)&At[row * 104 + c * 8] = *(const uint4*)(const void*)src;
    }
    for (int i = tid; i < NT * 12; i += 256) {
      int row = i / 12, c = i % 12;
      const ushort* src;
      if (MODE == 0)      src = W + ((size_t)kd * 384 + nb * 96 + row) * 96 + c * 8;
      else if (MODE == 1) src = W + ((size_t)kd * 256 + nb * 128 + row) * 192 + k0 + c * 8;
      else if (MODE == 2) src = W + ((size_t)kd * 96 + row) * 192 + k0 + c * 8;
      else if (MODE == 3) src = W + ((size_t)nb * 96 + row) * 96 + c * 8;
      else                src = W + (size_t)row * 384 + sp * 192 + k0 + c * 8;
      *(uint4*)(void*)&Wt[row * 104 + c * 8] = *(const uint4*)(const void*)src;
    }
    __syncthreads();
#pragma unroll
    for (int kk = 0; kk < 3; ++kk) {
      int ko = kk * 32 + (lane >> 4) * 8;
      bf16x8 afr[MF], bfr[NFR];
#pragma unroll
      for (int m = 0; m < MF; ++m)
        afr[m] = *(const bf16x8*)(void*)&At[(wvm * (MT / 2) + m * 16 + (lane & 15)) * 104 + ko];
#pragma unroll
      for (int n = 0; n < NFR; ++n)
        bfr[n] = *(const bf16x8*)(void*)&Wt[(wvn * NFR * 16 + n * 16 + (lane & 15)) * 104 + ko];
#pragma unroll
      for (int m = 0; m < MF; ++m)
#pragma unroll
        for (int n = 0; n < NFR; ++n)
          acc[m][n] = __builtin_amdgcn_mfma_f32_16x16x32_bf16(afr[m], bfr[n], acc[m][n], 0, 0, 0);
    }
    __syncthreads();
  }

  int col = lane & 15, rq = lane >> 4;
#pragma unroll
  for (int m = 0; m < MF; ++m) {
    int rl = wvm * (MT / 2) + m * 16 + rq * 4;
#pragma unroll
    for (int n = 0; n < NFR; ++n) {
      int j = nb * NT + wvn * NFR * 16 + n * 16 + col;
#pragma unroll
      for (int v = 0; v < 4; ++v) {
        float val = acc[m][n][v];
        size_t row = gm0 + rl + v;
        if (MODE == 0) {
          if (j < 192) u0[row * 192 + j] = f2bf(val);
          else u1[row * 192 + (j - 192)] = f2bf(val);
        } else if (MODE == 1) {
          if (j < 192) g0[row * 192 + j] = sp_softplus(val + f0[kd * 192 + j]);
          else if (j < 224) g1[row * 32 + (j - 192)] = val;
        } else if (MODE == 2) {
          g0[((size_t)kd * 8192 + row) * 96 + j] = val;
        } else if (MODE == 3) {
          float r_ = f3[row], m_ = f2[row];
          u0[row * 384 + j] = f2bf(gelu(r_ * val - r_ * m_ * f0[j] + f1[j]));
        } else {
          g0[((size_t)sp * 8192 + row) * 96 + j] = val;
        }
      }
    }
  }
}

// ============ K4: causal depthwise conv (k=4) + silu, bf16 in/out ============
__global__ void k_conv(const ushort* __restrict__ xsrb, const float* __restrict__ cw,
                       const float* __restrict__ cb, ushort* __restrict__ xsb) {
  int idx = blockIdx.x * blockDim.x + threadIdx.x;
  int d = idx % DI_;
  int rest = idx / DI_;
  int l = rest % L_;
  int kb = rest / L_;
  int k = kb / B_;
  float acc = cb[k * DI_ + d];
  const float* w = cw + ((size_t)k * DI_ + d) * 4;
#pragma unroll
  for (int j = 0; j < 4; ++j) {
    int t = l - 3 + j;
    if (t >= 0) acc += bf2f(xsrb[((size_t)kb * L_ + t) * DI_ + d]) * w[j];
  }
  xsb[idx] = f2bf(silu(acc));
}

// ============ K6: scan phase 1 (chunks of 32) ============
__global__ void k_scan1(const float* __restrict__ dlt, const ushort* __restrict__ xsb,
                        const float* __restrict__ xbc, const float* __restrict__ A_log,
                        float* __restrict__ Pb, float* __restrict__ Sb) {
  int blk = blockIdx.x;
  int c = blk % NC_;
  int kb = blk / NC_;
  int k = kb / B_;
  int d = threadIdx.x;  // 192
  __shared__ float Bs[CH_][DS_];
  for (int i = threadIdx.x; i < CH_ * DS_; i += DI_) {
    int t = i / DS_, n = i % DS_;
    Bs[t][n] = xbc[((size_t)kb * L_ + c * CH_ + t) * 32 + n];
  }
  float A2[DS_];
  const float* al = A_log + ((size_t)k * DI_ + d) * DS_;
#pragma unroll
  for (int n = 0; n < DS_; ++n) A2[n] = -expf(al[n]) * 1.4426950408889634f;
  __syncthreads();
  float h[DS_];
#pragma unroll
  for (int n = 0; n < DS_; ++n) h[n] = 0.f;
  float sumd = 0.f;
  const size_t rowb = ((size_t)kb * L_ + c * CH_) * DI_ + d;
  for (int t = 0; t < CH_; ++t) {
    float de = dlt[rowb + (size_t)t * DI_];
    float xv = bf2f(xsb[rowb + (size_t)t * DI_]);
    float dx = de * xv;
    sumd += de;
#pragma unroll
    for (int n = 0; n < DS_; ++n)
      h[n] = fmaf(exp2f(A2[n] * de), h[n], dx * Bs[t][n]);
  }
  size_t base = (((size_t)kb * NC_ + c) * DI_ + d) * DS_;
#pragma unroll
  for (int n = 0; n < DS_; ++n) {
    Pb[base + n] = exp2f(A2[n] * sumd);
    Sb[base + n] = h[n];
  }
}

// ============ K7: scan phase 2 — serial chunk combine ============
__global__ void k_scan2(const float* __restrict__ Pb, float* __restrict__ Sb) {
  int gid = blockIdx.x * blockDim.x + threadIdx.x;  // 24576
  int dn = gid % (DI_ * DS_);
  int kb = gid / (DI_ * DS_);
  size_t base = (size_t)kb * NC_ * DI_ * DS_ + dn;
  float h = 0.f;
  for (int c = 0; c < NC_; ++c) {
    size_t i = base + (size_t)c * DI_ * DS_;
    float p = Pb[i], s = Sb[i];
    Sb[i] = h;
    h = fmaf(p, h, s);
  }
}

// ============ K8: scan phase 3 — fused y=(scan+xs*D)*silu(z) -> gb bf16 ============
__global__ void k_scan3(const float* __restrict__ dlt, const ushort* __restrict__ xsb,
                        const float* __restrict__ xbc, const float* __restrict__ A_log,
                        const float* __restrict__ hin, const float* __restrict__ Dpp,
                        const ushort* __restrict__ zbb, ushort* __restrict__ gb) {
  int blk = blockIdx.x;
  int c = blk % NC_;
  int kb = blk / NC_;
  int k = kb / B_;
  int d = threadIdx.x;  // 192
  __shared__ float Bs[CH_][DS_], Cs[CH_][DS_];
  for (int i = threadIdx.x; i < CH_ * DS_; i += DI_) {
    int t = i / DS_, n = i % DS_;
    size_t rb = ((size_t)kb * L_ + c * CH_ + t) * 32;
    Bs[t][n] = xbc[rb + n];
    Cs[t][n] = xbc[rb + 16 + n];
  }
  float A2[DS_];
  const float* al = A_log + ((size_t)k * DI_ + d) * DS_;
#pragma unroll
  for (int n = 0; n < DS_; ++n) A2[n] = -expf(al[n]) * 1.4426950408889634f;
  float h[DS_];
  size_t hbase = (((size_t)kb * NC_ + c) * DI_ + d) * DS_;
#pragma unroll
  for (int n = 0; n < DS_; ++n) h[n] = hin[hbase + n];
  float Dv = Dpp[k * DI_ + d];
  __syncthreads();
  const size_t rowb = ((size_t)kb * L_ + c * CH_) * DI_ + d;
  for (int t = 0; t < CH_; ++t) {
    float de = dlt[rowb + (size_t)t * DI_];
    float xv = bf2f(xsb[rowb + (size_t)t * DI_]);
    float dx = de * xv;
    float acc = 0.f;
#pragma unroll
    for (int n = 0; n < DS_; ++n) {
      h[n] = fmaf(exp2f(A2[n] * de), h[n], dx * Bs[t][n]);
      acc = fmaf(h[n], Cs[t][n], acc);
    }
    float y = acc + xv * Dv;
    float zv = bf2f(zbb[rowb + (size_t)t * DI_]);
    gb[rowb + (size_t)t * DI_] = f2bf(y * silu(zv));
  }
}

// ============ K10: combine outmerge partials + x residual, fused LN2 ============
__global__ __launch_bounds__(256) void k_comb1(const float* __restrict__ pout, const float* __restrict__ mb,
                                               const float* __restrict__ x, float* __restrict__ xr,
                                               ushort* __restrict__ xrb, float* __restrict__ ms,
                                               float* __restrict__ rs) {
  int g0 = blockIdx.x * 64;
  int b = g0 >> 12, sB = g0 & 4095;
  int tid = threadIdx.x;
  __shared__ float Xs[64 * 97];
  for (int i = tid; i < 64 * 96; i += 256) {
    int row = i / 96, c = i % 96;
    size_t ro = (size_t)(g0 + row) * 96 + c;
    Xs[row * 97 + c] = pout[ro] + pout[ro + 786432] + pout[ro + 1572864] + pout[ro + 2359296] + mb[c];
  }
  __syncthreads();
  for (int i = tid; i < 64 * 96; i += 256) {
    int c = i / 64, sq = i % 64;
    Xs[sq * 97 + c] += x[((size_t)b * 96 + c) * 4096 + sB + sq];
  }
  __syncthreads();
  {
    int row = tid >> 2, q = tid & 3;
    float s1 = 0.f, s2 = 0.f;
    for (int c = q; c < 96; c += 4) {
      float v = Xs[row * 97 + c];
      s1 += v; s2 += v * v;
    }
    s1 += __shfl_xor(s1, 1); s1 += __shfl_xor(s1, 2);
    s2 += __shfl_xor(s2, 1); s2 += __shfl_xor(s2, 2);
    if (q == 0) {
      float m = s1 * (1.f / 96.f);
      ms[g0 + row] = m;
      rs[g0 + row] = rsqrtf(s2 * (1.f / 96.f) - m * m + 1e-5f);
    }
  }
  for (int i = tid; i < 64 * 96; i += 256) {
    int row = i / 96, c = i % 96;
    float v = Xs[row * 97 + c];
    xr[(size_t)(g0 + row) * 96 + c] = v;
    xrb[(size_t)(g0 + row) * 96 + c] = f2bf(v);
  }
}

// ============ K13: combine ffn2 partials + residual, transpose-store ============
__global__ __launch_bounds__(256) void k_comb2(const float* __restrict__ pf, const float* __restrict__ b2,
                                               const float* __restrict__ xr, float* __restrict__ out) {
  int g0 = blockIdx.x * 64;
  int b = g0 >> 12, sB = g0 & 4095;
  int tid = threadIdx.x;
  __shared__ float Xs[96 * 65];
  for (int i = tid; i < 64 * 96; i += 256) {
    int row = i / 96, c = i % 96;
    size_t ro = (size_t)(g0 + row) * 96 + c;
    Xs[c * 65 + row] = pf[ro] + pf[ro + 786432] + b2[c] + xr[ro];
  }
  __syncthreads();
  for (int i = tid; i < 64 * 96; i += 256) {
    int c = i / 64, sq = i % 64;
    out[((size_t)b * 96 + c) * 4096 + sB + sq] = Xs[c * 65 + sq];
  }
}

extern "C" void kernel_launch(void* const* d_in, const int* in_sizes, int n_in,
                              void* d_out, int out_size, void* d_ws, size_t ws_size,
                              hipStream_t stream) {
  const float* x       = (const float*)d_in[0];
  const float* norm_g  = (const float*)d_in[1];
  const float* norm_b  = (const float*)d_in[2];
  const float* in_w    = (const float*)d_in[3];
  const float* conv_w  = (const float*)d_in[4];
  const float* conv_b  = (const float*)d_in[5];
  const float* xproj_w = (const float*)d_in[6];
  const float* dt_w    = (const float*)d_in[7];
  const float* dt_b    = (const float*)d_in[8];
  const float* A_log   = (const float*)d_in[9];
  const float* Dp      = (const float*)d_in[10];
  const float* out_w   = (const float*)d_in[11];
  const float* merge_w = (const float*)d_in[12];
  const float* merge_b = (const float*)d_in[13];
  const float* ffn_g   = (const float*)d_in[14];
  const float* ffn_be  = (const float*)d_in[15];
  const float* ffn_w1  = (const float*)d_in[16];
  const float* ffn_b1  = (const float*)d_in[17];
  const float* ffn_w2  = (const float*)d_in[18];
  const float* ffn_b2  = (const float*)d_in[19];
  float* out = (float*)d_out;

  // workspace (float units), total 23,708,416 f = 94.8 MB
  float* ws = (float*)d_ws;
  ushort* xnb = (ushort*)(ws + 0);            // 786432 u
  ushort* wbu = (ushort*)(ws + 393216);       // 491520 u
  float*  ug  = ws + 638976;                  // 384 f
  float*  vb  = ws + 639360;                  // 384 f
  ushort* xsrb= (ushort*)(ws + 639744);       // 6291456 u  (-> gbu)
  ushort* zbb = (ushort*)(ws + 3785472);      // 6291456 u
  ushort* xsb = (ushort*)(ws + 6931200);      // 6291456 u  (-> xr/xrb/ms/rs)
  float*  dlt = ws + 10076928;                // 6291456 f  (-> pout)
  float*  xbc = ws + 16368384;                // 1048576 f
  float*  Pb  = ws + 17416960;                // 3145728 f  (-> pffn)
  float*  Sb  = ws + 20562688;                // 3145728 f  (-> hb)
  // weight sub-pointers
  ushort* in_wb = wbu;
  ushort* Wf    = wbu + 147456;
  ushort* W1p   = wbu + 344064;
  ushort* w2b   = wbu + 380928;
  ushort* Wkm   = wbu + 417792;
  // stream-ordered aliases (all within the dead xsb region [6931200, 10076928)):
  ushort* gbu  = xsrb;
  float*  pout = dlt;
  float*  xr   = ws + 6931200;                // 786432 f  -> [6931200, 7717632)
  ushort* xrb  = (ushort*)(ws + 7717632);     // 786432 u  -> [7717632, 8110848)
  float*  ms   = ws + 8110848;                // 8192 f    -> [8110848, 8119040)
  float*  rs   = ws + 8119040;                // 8192 f    -> [8119040, 8127232)
  float*  pffn = Pb;
  ushort* hb   = (ushort*)Sb;

  k_ln   <<<128, 256, 0, stream>>>(x, norm_g, norm_b, xnb);
  k_prepw<<<1632, 256, 0, stream>>>(in_w, dt_w, xproj_w, ffn_w1, ffn_g, ffn_w2, wbu);
  k_prepm<<<291, 256, 0, stream>>>(merge_w, out_w, ffn_w1, ffn_g, ffn_be, ffn_b1, Wkm, ug, vb);
  k_gemm<0, 96, 3, 4, 128><<<1024, 256, 0, stream>>>(xnb, in_wb, nullptr, nullptr, nullptr, nullptr,
                                                     nullptr, nullptr, xsrb, zbb);
  k_conv <<<24576, 256, 0, stream>>>(xsrb, conv_w, conv_b, xsb);
  k_gemm<1, 192, 4, 2, 128><<<512, 256, 0, stream>>>(xsb, Wf, dt_b, nullptr, nullptr, nullptr,
                                                     dlt, xbc, nullptr, nullptr);
  k_scan1<<<ND_ * B_ * NC_, DI_, 0, stream>>>(dlt, xsb, xbc, A_log, Pb, Sb);
  k_scan2<<<96, 256, 0, stream>>>(Pb, Sb);
  k_scan3<<<ND_ * B_ * NC_, DI_, 0, stream>>>(dlt, xsb, xbc, A_log, Sb, Dp, zbb, gbu);
  k_gemm<2, 192, 3, 1, 64><<<512, 256, 0, stream>>>(gbu, Wkm, nullptr, nullptr, nullptr, nullptr,
                                                    pout, nullptr, nullptr, nullptr);
  k_comb1<<<128, 256, 0, stream>>>(pout, merge_b, x, xr, xrb, ms, rs);
  k_gemm<3, 96, 3, 4, 64><<<512, 256, 0, stream>>>(xrb, W1p, ug, vb, ms, rs,
                                                   nullptr, nullptr, hb, nullptr);
  k_gemm<4, 192, 3, 1, 64><<<256, 256, 0, stream>>>(hb, w2b, nullptr, nullptr, nullptr, nullptr,
                                                    pffn, nullptr, nullptr, nullptr);
  k_comb2<<<128, 256, 0, stream>>>(pffn, ffn_b2, xr, out);
}